// Round 7
// baseline (1723.236 us; speedup 1.0000x reference)
//
#include <hip/hip_runtime.h>

// VGG_SMALL_1W1A on MI355X — R16.
// R12..R15 all pinned the top dispatch at 112-114 us (MfmaUtil ~44) — the
// 2-phase chunk structure's ceiling. R16 reduces the WORK instead: with
// 4 waves per wn, every B fragment was read 4x from LDS (64 b128/CU/tap
// ~ 770 cyc vs MFMA 465 cyc/SIMD — LDS was the larger serial term).
// New wave map: wm=wave&1 (64 Cout rows, acc[4][2]), wn=wave>>1 (32 cols,
// ni 0..1) -> B reads halve to 32 b128/CU/tap (~385 cyc); bank conflicts
// halve; MFMA count unchanged. A-reads double but are L1-resident.
// Pool pairs must stay intra-wave: W=16 (pairs ni0/ni1), W=8 (shfl 8/1)
// survive directly; W=32 gets a custom lane map — wave wn owns
// w in [8wn,8wn+8) x all 4 h rows, l15=(h&1)*8+(w&7), h-pair=shfl_xor(8),
// w-pair=shfl_xor(1). Keep R15's sched_barrier(0)+setprio (best total).

typedef unsigned short u16;
typedef __attribute__((ext_vector_type(8))) short short8;
typedef __attribute__((ext_vector_type(8))) unsigned short ushort8;
typedef __attribute__((ext_vector_type(4))) unsigned short ushort4v;
typedef __attribute__((ext_vector_type(4))) float float4v;

__device__ __forceinline__ float bf2f(u16 u) { return __uint_as_float(((unsigned)u) << 16); }
__device__ __forceinline__ u16 f2bf(float f) {
    unsigned u = __float_as_uint(f);
    return (u16)((u + 0x7FFFu + ((u >> 16) & 1u)) >> 16);
}
__device__ __forceinline__ u16 lo_bf(float y, u16 hi) {  // bf16(y - fl(hi))
    return f2bf(y - bf2f(hi));
}
__device__ __forceinline__ u16 signbf(float y) {
    return y > 0.f ? 0x3F80u : (y < 0.f ? 0xBF80u : 0u);
}

// ---------------- conv0_main: 3->128, 32x32, direct fp32, fp32 NHWC out ----------------
__global__ __launch_bounds__(256) void conv0_main(const float* __restrict__ x,
                                                  const float* __restrict__ w0,
                                                  float* __restrict__ out) {
    __shared__ float xt[306];     // [ci][kh][w+2pad], 34-stride rows
    __shared__ float wl[3456];    // 128*27
    const int t = threadIdx.x;
    const int n = blockIdx.x >> 5;
    const int h = blockIdx.x & 31;
    for (int i = t; i < 306; i += 256) xt[i] = 0.f;
    for (int i = t; i < 3456; i += 256) wl[i] = w0[i];
    __syncthreads();
    for (int i = t; i < 288; i += 256) {
        int ci = i / 96; int rr = (i / 32) % 3; int w = i & 31;
        int gh = h - 1 + rr;
        if (gh >= 0 && gh < 32)
            xt[(ci * 3 + rr) * 34 + w + 1] = x[((n * 3 + ci) * 32 + gh) * 32 + w];
    }
    __syncthreads();
    const int w = t & 31, cg = t >> 5;
    float xin[27];
#pragma unroll
    for (int ci = 0; ci < 3; ci++)
#pragma unroll
        for (int r = 0; r < 3; r++)
#pragma unroll
            for (int kw = 0; kw < 3; kw++)
                xin[(ci * 3 + r) * 3 + kw] = xt[(ci * 3 + r) * 34 + w + kw];
    float* o = out + ((size_t)(n * 1024 + h * 32 + w)) * 128 + cg * 16;
#pragma unroll
    for (int jq = 0; jq < 4; jq++) {
        float4v v;
#pragma unroll
        for (int jk = 0; jk < 4; jk++) {
            int co = cg * 16 + jq * 4 + jk;
            float a = 0.f;
#pragma unroll
            for (int e = 0; e < 27; e++) a += xin[e] * wl[co * 27 + e];
            v[jk] = a;
        }
        *(float4v*)(o + jq * 4) = v;
    }
}

// ---------------- stats over fp32 NHWC (stage 0) ----------------
__global__ __launch_bounds__(256) void stats0_kernel(const float* __restrict__ src,
                                                     float* __restrict__ st,
                                                     int C, int rows_per_block) {
    const int t = threadIdx.x;
    const int c = blockIdx.x * 64 + (t & 63);
    const int rg = t >> 6;
    const int r0 = blockIdx.y * rows_per_block;
    float s = 0.f, q = 0.f;
    for (int r = r0 + rg; r < r0 + rows_per_block; r += 4) {
        float v = src[(size_t)r * C + c];
        s += v;
        q += v * v;
    }
    __shared__ float Ls[256], Lq[256];
    Ls[t] = s; Lq[t] = q;
    __syncthreads();
    if (t < 64) {
        s = Ls[t] + Ls[t + 64] + Ls[t + 128] + Ls[t + 192];
        q = Lq[t] + Lq[t + 64] + Lq[t + 128] + Lq[t + 192];
        atomicAdd(&st[c], s);
        atomicAdd(&st[C + c], q);
    }
}

// ---------------- bn0_apply: fp32 conv0-out -> sign acts + real hi/lo acts ----------------
__global__ __launch_bounds__(256) void bn0_apply(const float* __restrict__ src,
                                                 const float* __restrict__ st,
                                                 const float* __restrict__ g,
                                                 const float* __restrict__ b,
                                                 u16* __restrict__ sg,
                                                 u16* __restrict__ hi,
                                                 u16* __restrict__ lo) {
    const int t = threadIdx.x;
    __shared__ float sc[128], sh[128];
    if (t < 128) {
        float mean = st[t] * (1.f / 131072.f);
        float var = fmaxf(st[128 + t] * (1.f / 131072.f) - mean * mean, 0.f);
        float scale = rsqrtf(var + 1e-5f) * g[t];
        sc[t] = scale;
        sh[t] = b[t] - mean * scale;
    }
    __syncthreads();
    size_t i = ((size_t)blockIdx.x * 256 + t) * 4;
    int c0 = (int)(i & 127);
    float4v v = *(const float4v*)(src + i);
    ushort4v hv, lv, sv;
#pragma unroll
    for (int k = 0; k < 4; k++) {
        float y = fminf(fmaxf(v[k] * sc[c0 + k] + sh[c0 + k], -1.f), 1.f);
        hv[k] = f2bf(y);
        lv[k] = lo_bf(y, hv[k]);
        sv[k] = signbf(y);
    }
    *(ushort4v*)(sg + i) = sv;
    *(ushort4v*)(hi + i) = hv;
    *(ushort4v*)(lo + i) = lv;
}

// ---------------- weight prepack; BIN = standardize+sign, else hi+lo split ----------------
template <bool BIN>
__global__ __launch_bounds__(256) void prepack_kernel(const float* __restrict__ w,
                                                      u16* __restrict__ apk,
                                                      u16* __restrict__ apkLo,
                                                      int Cin, int Cout) {
    const int t = threadIdx.x, o = blockIdx.x;
    const int E = Cin * 9;
    float m = 0.f;
    if (BIN) {
        float s = 0.f;
        for (int e = t; e < E; e += 256) s += w[o * E + e];
        __shared__ float Ls[256];
        Ls[t] = s;
        __syncthreads();
        for (int stp = 128; stp > 0; stp >>= 1) {
            if (t < stp) Ls[t] += Ls[t + stp];
            __syncthreads();
        }
        m = Ls[0] / (float)E;
    }
    const int CC = Cin >> 5, COT = Cout >> 7;
    for (int e = t; e < E; e += 256) {
        int ci = e / 9, tap = e % 9;
        float raw = w[o * E + e];
        int idx = ((tap * CC + (ci >> 5)) * COT + (o >> 7)) * 4096 + (o & 127) * 32 + (ci & 31);
        if (BIN) {
            apk[idx] = signbf(raw - m);
        } else {
            u16 hi = f2bf(raw);
            apk[idx] = hi;
            apkLo[idx] = lo_bf(raw, hi);
        }
    }
}

// ---------------- implicit-GEMM MFMA conv (8 waves / 512 threads) ----------------
// Wave map: wm = wave&1 (64 Cout rows -> acc[4][2], mi 0..3), wn = wave>>1
// (32 cols, ni 0..1). B LDS reads: 4 b128/wave/tap (halved vs R15).
// A direct from prepacked global (ping-pong); B reg ping-pong from dbuf
// LDS; per-tap sched_barrier(0) fence + setprio around MFMA cluster.
// W==32 lane map: w = wn*8+(l15&7), h = ni*2+(l15>>3) so pool pairs are
// shfl_xor(8) (h) and shfl_xor(1) (w) intra-wave.
template <bool POOL, bool BIN>
__global__ __launch_bounds__(512, 2) void conv_mfma_kernel(
    const u16* __restrict__ act, const u16* __restrict__ actLo,
    const u16* __restrict__ apk, const u16* __restrict__ apkLo,
    u16* __restrict__ out, u16* __restrict__ outLo,
    int Cin, int Cout, int H, int W) {
    const int HW = H * W;
    const int t = threadIdx.x;
    const int wave = t >> 6, lane = t & 63;
    const int l15 = lane & 15, quad = lane >> 4;
    const int wm = wave & 1, wn = wave >> 1;   // wm: 64 co rows; wn: 32 cols

    const int col0 = blockIdx.x * 128;
    const int cot = blockIdx.y;
    const int CC = Cin >> 5;
    const int COT = Cout >> 7;
    const bool two = (HW < 128);          // 128 cols span two images (HW==64)
    const int Wp = W + 2;
    const int nrows = two ? 2 * (H + 2) : (128 / W + 2);
    const int n0 = col0 / HW;
    const int h0 = two ? 0 : (col0 % HW) / W;

    __shared__ __align__(16) u16 BsH[2][8160];                       // dbuf [cell][40]
    __shared__ __align__(16) u16 BsL[BIN ? 1 : 2][BIN ? 16 : 8160];

    int bbase[2], gcol[2];
    if (W == 32) {
        // custom lane map: keep pool h/w pairs intra-wave
#pragma unroll
        for (int ni = 0; ni < 2; ni++) {
            int hl = ni * 2 + (l15 >> 3);
            int w = wn * 8 + (l15 & 7);
            gcol[ni] = n0 * HW + (h0 + hl) * W + w;
            bbase[ni] = (hl * Wp + w) * 40 + quad * 8;
        }
    } else {
#pragma unroll
        for (int ni = 0; ni < 2; ni++) {
            int c = wn * 32 + ni * 16 + l15;
            int g = col0 + c;
            int n = g / HW; int hw = g % HW; int h = hw / W; int w = hw % W;
            gcol[ni] = g;
            int rb = two ? ((n - n0) * (H + 2) + h) : (h - h0);
            bbase[ni] = (rb * Wp + w) * 40 + quad * 8;
        }
    }

    // ---- hoisted B-staging address math (cc-invariant) ----
    const int bgroups = nrows * Wp * 4;   // <= 1024 for all stages
    int svalid[2]; size_t sgoff[2]; int sloff[2];
#pragma unroll
    for (int j = 0; j < 2; j++) {
        int idx = t + j * 512;
        svalid[j] = 0; sgoff[j] = 0; sloff[j] = 0;
        if (idx < bgroups) {
            int cig = idx & 3;
            int rest = idx >> 2;
            int wp = rest % Wp;
            int srow = rest / Wp;
            int n, gh;
            if (two) { n = n0 + srow / (H + 2); gh = srow % (H + 2) - 1; }
            else     { n = n0; gh = h0 + srow - 1; }
            int gw = wp - 1;
            sloff[j] = (srow * Wp + wp) * 40 + cig * 8;
            if (gh >= 0 && gh < H && gw >= 0 && gw < W) {
                svalid[j] = 2;
                sgoff[j] = ((size_t)(n * HW + gh * W + gw)) * Cin + cig * 8;
            } else {
                svalid[j] = 1;   // in-range LDS cell, zero fill
            }
        }
    }

    float4v acc[4][2];
    const float4v zf = {0.f, 0.f, 0.f, 0.f};
#pragma unroll
    for (int mi = 0; mi < 4; mi++)
#pragma unroll
        for (int ni = 0; ni < 2; ni++) acc[mi][ni] = zf;

    const size_t tapstride = (size_t)CC * COT * 4096;
    // A-fragment offset within a tap tile: (wm*64 + l15) rows of 32 ci
    const int arow0 = wm * 2048 + l15 * 32 + quad * 8;

    short8 ahP[2][4];                     // ping-pong A-hi frags (mi 0..3)
    short8 alP[2][4];                     // ping-pong A-lo frags (real only)
    short8 ah0N[4], al0N[4];              // cross-chunk tap-0 A prefetch
    short8 bhP[2][2];                     // ping-pong B-hi frags (ni 0..1)
    short8 blP[2][2];                     // ping-pong B-lo frags (real only)
    short8 svh[2], svl[2];                // reg-staged B for next chunk
    const short8 z8 = {0, 0, 0, 0, 0, 0, 0, 0};

    // ---- prologue: stage chunk 0 into buf 0, load tap-0 A, then tap-0 B frags ----
    {
        const u16* ab0 = apk + ((size_t)cot) * 4096;
        const u16* ab0L = apkLo + ((size_t)cot) * 4096;
#pragma unroll
        for (int mi = 0; mi < 4; mi++) {
            ahP[0][mi] = *(const short8*)(ab0 + arow0 + mi * 512);
            if (!BIN) alP[0][mi] = *(const short8*)(ab0L + arow0 + mi * 512);
        }
#pragma unroll
        for (int j = 0; j < 2; j++) {
            svh[j] = z8; svl[j] = z8;
            if (svalid[j] == 2) {
                svh[j] = *(const short8*)(act + sgoff[j]);
                if (!BIN) svl[j] = *(const short8*)(actLo + sgoff[j]);
            }
        }
#pragma unroll
        for (int j = 0; j < 2; j++) {
            if (svalid[j]) {
                *(short8*)&BsH[0][sloff[j]] = svh[j];
                if (!BIN) *(short8*)&BsL[0][sloff[j]] = svl[j];
            }
        }
        __syncthreads();
        // tap-0 B fragments (boff = 0)
#pragma unroll
        for (int ni = 0; ni < 2; ni++) {
            bhP[0][ni] = *(const short8*)&BsH[0][bbase[ni]];
            if (!BIN) blP[0][ni] = *(const short8*)&BsL[0][bbase[ni]];
        }
    }

    for (int cc = 0; cc < CC; cc++) {
        const int cur = cc & 1, nx = cur ^ 1;
        const bool more = (cc + 1 < CC);
        const u16* ab = apk + ((size_t)(cc * COT + cot)) * 4096;
        const u16* abL = apkLo + ((size_t)(cc * COT + cot)) * 4096;

        // issue next chunk's B global loads + tap-0 A loads (consumed after taps)
        if (more) {
            const size_t ccb = (size_t)(cc + 1) * 32;
#pragma unroll
            for (int j = 0; j < 2; j++) {
                svh[j] = z8; svl[j] = z8;
                if (svalid[j] == 2) {
                    svh[j] = *(const short8*)(act + sgoff[j] + ccb);
                    if (!BIN) svl[j] = *(const short8*)(actLo + sgoff[j] + ccb);
                }
            }
            const u16* abN = apk + ((size_t)((cc + 1) * COT + cot)) * 4096;
            const u16* abNL = apkLo + ((size_t)((cc + 1) * COT + cot)) * 4096;
#pragma unroll
            for (int mi = 0; mi < 4; mi++) {
                ah0N[mi] = *(const short8*)(abN + arow0 + mi * 512);
                if (!BIN) al0N[mi] = *(const short8*)(abNL + arow0 + mi * 512);
            }
        }

#pragma unroll
        for (int tap = 0; tap < 9; tap++) {
            const int curp = tap & 1, nxp = curp ^ 1;
            if (tap < 8) {
                // A prefetch tap+1 (global, L1-resident)
                const u16* at = ab + (size_t)(tap + 1) * tapstride;
#pragma unroll
                for (int mi = 0; mi < 4; mi++)
                    ahP[nxp][mi] = *(const short8*)(at + arow0 + mi * 512);
                if (!BIN) {
                    const u16* atL = abL + (size_t)(tap + 1) * tapstride;
#pragma unroll
                    for (int mi = 0; mi < 4; mi++)
                        alP[nxp][mi] = *(const short8*)(atL + arow0 + mi * 512);
                }
                // B prefetch tap+1 (LDS)
                const int kh1 = (tap + 1) / 3, kw1 = (tap + 1) % 3;
                const int boff1 = (kh1 * Wp + kw1) * 40;
#pragma unroll
                for (int ni = 0; ni < 2; ni++) {
                    bhP[nxp][ni] = *(const short8*)&BsH[cur][bbase[ni] + boff1];
                    if (!BIN) blP[nxp][ni] = *(const short8*)&BsL[cur][bbase[ni] + boff1];
                }
            }
            // hard fence: prefetch issues above cannot sink below; MFMAs
            // below cannot hoist above.
            __builtin_amdgcn_sched_barrier(0);
            __builtin_amdgcn_s_setprio(1);
            if (BIN) {
#pragma unroll
                for (int mi = 0; mi < 4; mi++)
#pragma unroll
                    for (int ni = 0; ni < 2; ni++)
                        acc[mi][ni] = __builtin_amdgcn_mfma_f32_16x16x32_bf16(
                            ahP[curp][mi], bhP[curp][ni], acc[mi][ni], 0, 0, 0);
            } else {
                // three 8-MFMA sweeps: each acc has dep distance 8
#pragma unroll
                for (int mi = 0; mi < 4; mi++)
#pragma unroll
                    for (int ni = 0; ni < 2; ni++)
                        acc[mi][ni] = __builtin_amdgcn_mfma_f32_16x16x32_bf16(
                            ahP[curp][mi], bhP[curp][ni], acc[mi][ni], 0, 0, 0);
#pragma unroll
                for (int mi = 0; mi < 4; mi++)
#pragma unroll
                    for (int ni = 0; ni < 2; ni++)
                        acc[mi][ni] = __builtin_amdgcn_mfma_f32_16x16x32_bf16(
                            ahP[curp][mi], blP[curp][ni], acc[mi][ni], 0, 0, 0);
#pragma unroll
                for (int mi = 0; mi < 4; mi++)
#pragma unroll
                    for (int ni = 0; ni < 2; ni++)
                        acc[mi][ni] = __builtin_amdgcn_mfma_f32_16x16x32_bf16(
                            alP[curp][mi], bhP[curp][ni], acc[mi][ni], 0, 0, 0);
            }
            __builtin_amdgcn_s_setprio(0);
        }

        if (more) {
            // write staged B into the other buffer, then one barrier
#pragma unroll
            for (int j = 0; j < 2; j++) {
                if (svalid[j]) {
                    *(short8*)&BsH[nx][sloff[j]] = svh[j];
                    if (!BIN) *(short8*)&BsL[nx][sloff[j]] = svl[j];
                }
            }
            __syncthreads();
            // install prefetched tap-0 A and load tap-0 B frags for next chunk
#pragma unroll
            for (int mi = 0; mi < 4; mi++) {
                ahP[0][mi] = ah0N[mi];
                if (!BIN) alP[0][mi] = al0N[mi];
            }
#pragma unroll
            for (int ni = 0; ni < 2; ni++) {
                bhP[0][ni] = *(const short8*)&BsH[nx][bbase[ni]];
                if (!BIN) blP[0][ni] = *(const short8*)&BsL[nx][bbase[ni]];
            }
        }
    }

    const int cobase = cot * 128 + wm * 64 + quad * 4;
    // store helper: BIN -> int16 exact; real -> bf16 hi + bf16 lo
    auto store4 = [&](size_t off, float4v v) {
        if (BIN) {
            ushort4v r;
#pragma unroll
            for (int k = 0; k < 4; k++) r[k] = (u16)(short)(int)v[k];
            *(ushort4v*)(out + off) = r;
        } else {
            ushort4v hi, lo;
#pragma unroll
            for (int k = 0; k < 4; k++) {
                hi[k] = f2bf(v[k]);
                lo[k] = lo_bf(v[k], hi[k]);
            }
            *(ushort4v*)(out + off) = hi;
            *(ushort4v*)(outLo + off) = lo;
        }
    };

    if (!POOL) {
#pragma unroll
        for (int mi = 0; mi < 4; mi++)
#pragma unroll
            for (int ni = 0; ni < 2; ni++)
                store4((size_t)gcol[ni] * Cout + cobase + mi * 16, acc[mi][ni]);
    } else {
        const int pH = H >> 1, pW = W >> 1;
        if (W == 32) {
            // h-pair = shfl_xor(8), w-pair = shfl_xor(1)
#pragma unroll
            for (int mi = 0; mi < 4; mi++)
#pragma unroll
                for (int ni = 0; ni < 2; ni++) {
                    float4v v = acc[mi][ni];
#pragma unroll
                    for (int k = 0; k < 4; k++) {
                        float vv = v[k];
                        vv = fmaxf(vv, __shfl_xor(vv, 8, 64));
                        v[k] = fmaxf(vv, __shfl_xor(vv, 1, 64));
                    }
                    if ((l15 & 9) == 0) {
                        int pw = wn * 4 + ((l15 & 7) >> 1);
                        int ph = (h0 >> 1) + ni;
                        int prow = (n0 * pH + ph) * pW + pw;
                        store4((size_t)prow * Cout + cobase + mi * 16, v);
                    }
                }
        } else if (W == 16) {
            // h-pair = (ni 0, ni 1); w-pair = shfl_xor(1)
#pragma unroll
            for (int mi = 0; mi < 4; mi++) {
                float4v v;
#pragma unroll
                for (int k = 0; k < 4; k++)
                    v[k] = fmaxf((float)acc[mi][0][k], (float)acc[mi][1][k]);
#pragma unroll
                for (int k = 0; k < 4; k++) {
                    float vv = v[k];
                    v[k] = fmaxf(vv, __shfl_xor(vv, 1, 64));
                }
                if ((l15 & 1) == 0) {
                    int pw = l15 >> 1;
                    int ph = (h0 >> 1) + wn;
                    int prow = (n0 * pH + ph) * pW + pw;
                    store4((size_t)prow * Cout + cobase + mi * 16, v);
                }
            }
        } else {  // W == 8, two-image: h-pair = shfl_xor(8), w-pair = shfl_xor(1)
#pragma unroll
            for (int mi = 0; mi < 4; mi++)
#pragma unroll
                for (int ni = 0; ni < 2; ni++) {
                    float4v v = acc[mi][ni];
#pragma unroll
                    for (int k = 0; k < 4; k++) {
                        float vv = v[k];
                        vv = fmaxf(vv, __shfl_xor(vv, 8, 64));
                        v[k] = fmaxf(vv, __shfl_xor(vv, 1, 64));
                    }
                    if ((l15 & 9) == 0) {
                        int pw = (l15 & 7) >> 1;
                        int ph = (wn & 1) * 2 + ni;
                        int n = n0 + (wn >> 1);
                        int prow = (n * pH + ph) * pW + pw;
                        store4((size_t)prow * Cout + cobase + mi * 16, v);
                    }
                }
        }
    }
}

// ---------------- per-channel batch stats (sum, sumsq); BIN=int16, real=hi+lo ----------------
template <bool BIN>
__global__ __launch_bounds__(256) void stats_kernel(const u16* __restrict__ src,
                                                    const u16* __restrict__ srcLo,
                                                    float* __restrict__ st,
                                                    int C, int rows_per_block) {
    const int t = threadIdx.x;
    const int c = blockIdx.x * 64 + (t & 63);
    const int rg = t >> 6;
    const int r0 = blockIdx.y * rows_per_block;
    float s = 0.f, q = 0.f;
    for (int r = r0 + rg; r < r0 + rows_per_block; r += 4) {
        size_t i = (size_t)r * C + c;
        float v = BIN ? (float)(short)src[i] : (bf2f(src[i]) + bf2f(srcLo[i]));
        s += v;
        q += v * v;
    }
    __shared__ float Ls[256], Lq[256];
    Ls[t] = s; Lq[t] = q;
    __syncthreads();
    if (t < 64) {
        s = Ls[t] + Ls[t + 64] + Ls[t + 128] + Ls[t + 192];
        q = Lq[t] + Lq[t + 64] + Lq[t + 128] + Lq[t + 192];
        atomicAdd(&st[c], s);
        atomicAdd(&st[C + c], q);
    }
}

// ---------------- BN + hardtanh; acts (mode 1=real hi+lo, 2=sign) + fp32 NCHW d_out ----------------
template <bool BIN>
__global__ __launch_bounds__(256) void bn_apply_kernel(const u16* __restrict__ src,
                                                       const u16* __restrict__ srcLo,
                                                       int C, int HW,
                                                       const float* __restrict__ st, float cntinv,
                                                       const float* __restrict__ g,
                                                       const float* __restrict__ b,
                                                       float* __restrict__ dout,
                                                       float* __restrict__ dout2,
                                                       u16* __restrict__ act,
                                                       u16* __restrict__ actLo,
                                                       int act_mode) {
    const int t = threadIdx.x;
    const int cl = t & 63, rl = t >> 6;
    const int c = blockIdx.y * 64 + cl;
    const float mean = st[c] * cntinv;
    float var = st[C + c] * cntinv - mean * mean;
    var = fmaxf(var, 0.f);
    const float scale = rsqrtf(var + 1e-5f) * g[c];
    const float shift = b[c] - mean * scale;
    __shared__ float T[64][65];
#pragma unroll
    for (int i = 0; i < 16; i++) {
        int rlocal = rl + i * 4;
        int row = blockIdx.x * 64 + rlocal;
        size_t idx = (size_t)row * C + c;
        float v = BIN ? (float)(short)src[idx] : (bf2f(src[idx]) + bf2f(srcLo[idx]));
        float y = fminf(fmaxf(v * scale + shift, -1.f), 1.f);
        if (act_mode == 1) {
            u16 hi = f2bf(y);
            act[idx] = hi;
            actLo[idx] = lo_bf(y, hi);
        } else if (act_mode == 2) {
            act[idx] = signbf(y);
        }
        T[rlocal][cl] = y;
    }
    __syncthreads();
#pragma unroll
    for (int i = 0; i < 16; i++) {
        int clocal = rl + i * 4;
        int cg = blockIdx.y * 64 + clocal;
        int rglob = blockIdx.x * 64 + cl;
        int n = rglob / HW, hw = rglob % HW;
        size_t o = ((size_t)n * C + cg) * HW + hw;
        float val = T[cl][clocal];
        dout[o] = val;
        if (dout2) dout2[o] = val;
    }
}

// ---------------- FC: [128,8192] @ [10,8192]^T + b (all fp32) ----------------
__global__ __launch_bounds__(256) void fc_kernel(const float* __restrict__ penul,
                                                 const float* __restrict__ fcw,
                                                 const float* __restrict__ fcb,
                                                 float* __restrict__ out) {
    const int t = threadIdx.x, n = blockIdx.x;
    float acc[10];
#pragma unroll
    for (int j = 0; j < 10; j++) acc[j] = 0.f;
    for (int i = t; i < 8192; i += 256) {
        float p = penul[n * 8192 + i];
#pragma unroll
        for (int j = 0; j < 10; j++) acc[j] += p * fcw[j * 8192 + i];
    }
    __shared__ float L[10][256];
#pragma unroll
    for (int j = 0; j < 10; j++) L[j][t] = acc[j];
    __syncthreads();
    for (int s = 128; s > 0; s >>= 1) {
        if (t < s) {
#pragma unroll
            for (int j = 0; j < 10; j++) L[j][t] += L[j][t + s];
        }
        __syncthreads();
    }
    if (t < 10) out[n * 10 + t] = L[t][0] + fcb[t];
}

extern "C" void kernel_launch(void* const* d_in, const int* in_sizes, int n_in,
                              void* d_out, int out_size, void* d_ws, size_t ws_size,
                              hipStream_t stream) {
    (void)in_sizes; (void)n_in; (void)out_size; (void)ws_size;

    const float* X = (const float*)d_in[0];
    const float* W0 = (const float*)d_in[1];
    const float* Wl[5] = {(const float*)d_in[2], (const float*)d_in[3], (const float*)d_in[4],
                          (const float*)d_in[5], (const float*)d_in[6]};
    const float* FCW = (const float*)d_in[7];
    const float* FCB = (const float*)d_in[8];
    const float* G[6]; const float* Bb[6];
    for (int i = 0; i < 6; i++) { G[i] = (const float*)d_in[9 + 2 * i]; Bb[i] = (const float*)d_in[10 + 2 * i]; }

    float* OUT = (float*)d_out;
    char* ws = (char*)d_ws;

    // ws layout (bytes), all disjoint, total 93,329,408 (R6-proven):
    u16* apk   = (u16*)(ws);               // [0,          4,718,592)
    u16* apkLo = (u16*)(ws + 4718592);     // [4,718,592,  9,437,184)
    float* st0 = (float*)(ws + 9437184);   // [9,437,184,  9,439,232)
    float* stk = (float*)(ws + 9439232);   // [9,439,232,  9,443,328)
    u16* F     = (u16*)(ws + 9443328);     // 8,388,608 elems (hi / int16)
    u16* Flo   = (u16*)(ws + 26220544);    // 8,388,608 elems (lo, real)
    u16* AB    = (u16*)(ws + 42997760);    // 8,388,608 elems
    u16* AR    = (u16*)(ws + 59774976);    // 8,388,608 elems
    u16* ARlo  = (u16*)(ws + 76552192);    // 8,388,608 elems

    // Stage-0 arenas: C0 in ws (F..AR range, dead until stage 1); sign acts SG
    // and real hi/lo acts in dead d_out regions (R8-proven lifetimes).
    float* C0 = (float*)(ws + 9443328);
    u16* SG   = (u16*)(OUT + 26215680);
    u16* X0   = (u16*)(OUT + 9438464);
    u16* X0lo = (u16*)(OUT + 17827072);

    float* O_out = OUT;
    float* O_pen = OUT + 1280;
    float* O_L1b = OUT + 1049856;
    float* O_L1r = OUT + 5244160;
    float* O_L2b = OUT + 9438464;
    float* O_L2r = OUT + 17827072;
    float* O_L3b = OUT + 26215680;
    float* O_L3r = OUT + 28312832;
    float* O_L4b = OUT + 30409984;
    float* O_L4r = OUT + 34604288;
    float* O_L5b = OUT + 38798592;
    float* O_L5r = OUT + 39847168;

    // ---- stage 0: conv0 (1 pass, fp32 -> ws) -> stats -> bn apply (sign + hi/lo)
    conv0_main<<<4096, 256, 0, stream>>>(X, W0, C0);
    hipMemsetAsync(st0, 0, 2048, stream);
    stats0_kernel<<<dim3(2, 256), 256, 0, stream>>>(C0, st0, 128, 512);
    bn0_apply<<<16384, 256, 0, stream>>>(C0, st0, G[0], Bb[0], SG, X0, X0lo);

    struct Stage {
        const float* w; int Cin, Cout, H, W; bool pool;
        dim3 cgrid; dim3 sgrid; int srpb; dim3 bgrid; int bHW; float cntinv;
        float* db; float* dr;
    };
    const Stage S[5] = {
        {Wl[0], 128, 128, 32, 32, true,  dim3(1024, 1), dim3(2, 64), 512, dim3(512, 2), 256, 1.f / 32768.f, O_L1b, O_L1r},
        {Wl[1], 128, 256, 16, 16, false, dim3(256, 2),  dim3(4, 64), 512, dim3(512, 4), 256, 1.f / 32768.f, O_L2b, O_L2r},
        {Wl[2], 256, 256, 16, 16, true,  dim3(256, 2),  dim3(4, 16), 512, dim3(128, 4), 64,  1.f / 8192.f,  O_L3b, O_L3r},
        {Wl[3], 256, 512, 8, 8,   false, dim3(64, 4),   dim3(8, 16), 512, dim3(128, 8), 64,  1.f / 8192.f,  O_L4b, O_L4r},
        {Wl[4], 512, 512, 8, 8,   true,  dim3(64, 4),   dim3(8, 16), 128, dim3(32, 8),  16,  1.f / 2048.f,  O_L5b, O_L5r},
    };

    for (int k = 0; k < 5; k++) {
        const Stage& s = S[k];
        const u16* inB = (k == 0) ? SG : AB;
        const u16* inR = (k == 0) ? X0 : AR;
        const u16* inRlo = (k == 0) ? X0lo : ARlo;

        // ---- binary branch (exact: sign weights/acts, int16 conv-out)
        prepack_kernel<true><<<s.Cout, 256, 0, stream>>>(s.w, apk, nullptr, s.Cin, s.Cout);
        if (s.pool) conv_mfma_kernel<true, true><<<s.cgrid, 512, 0, stream>>>(inB, nullptr, apk, apk, F, nullptr, s.Cin, s.Cout, s.H, s.W);
        else        conv_mfma_kernel<false, true><<<s.cgrid, 512, 0, stream>>>(inB, nullptr, apk, apk, F, nullptr, s.Cin, s.Cout, s.H, s.W);
        hipMemsetAsync(stk, 0, 4096, stream);
        stats_kernel<true><<<s.sgrid, 256, 0, stream>>>(F, nullptr, stk, s.Cout, s.srpb);
        bn_apply_kernel<true><<<s.bgrid, 256, 0, stream>>>(F, nullptr, s.Cout, s.bHW, stk, s.cntinv,
                                                           G[k + 1], Bb[k + 1], s.db,
                                                           (k == 4) ? O_pen : nullptr,
                                                           AB, nullptr, (k == 4) ? 0 : 2);

        // ---- real branch (single traversal, 3-term split-bf16; out hi+lo)
        prepack_kernel<false><<<s.Cout, 256, 0, stream>>>(s.w, apk, apkLo, s.Cin, s.Cout);
        if (s.pool) conv_mfma_kernel<true, false><<<s.cgrid, 512, 0, stream>>>(inR, inRlo, apk, apkLo, F, Flo, s.Cin, s.Cout, s.H, s.W);
        else        conv_mfma_kernel<false, false><<<s.cgrid, 512, 0, stream>>>(inR, inRlo, apk, apkLo, F, Flo, s.Cin, s.Cout, s.H, s.W);
        hipMemsetAsync(stk, 0, 4096, stream);
        stats_kernel<false><<<s.sgrid, 256, 0, stream>>>(F, Flo, stk, s.Cout, s.srpb);
        bn_apply_kernel<false><<<s.bgrid, 256, 0, stream>>>(F, Flo, s.Cout, s.bHW, stk, s.cntinv,
                                                            G[k + 1], Bb[k + 1], s.dr, nullptr,
                                                            AR, ARlo, (k == 4) ? 0 : 1);
    }

    // ---- fc
    fc_kernel<<<128, 256, 0, stream>>>(O_pen, FCW, FCB, O_out);
}

// Round 8
// 1418.329 us; speedup vs baseline: 1.2150x; 1.2150x over previous
//
#include <hip/hip_runtime.h>

// VGG_SMALL_1W1A on MI355X — R17.
// R16 (col-split wave map) regressed 1381->1723: halving B LDS reads
// doubled A L1 traffic (4x wn duplication) and the 4-deep A ping-pong was
// re-sunk (VGPR 108). REVERTED to R15 (best: 1381 us, top dispatch 113.6).
// R17's single change: ANTI-PHASE TAP ROTATION. All 8 waves ran the tap
// loop in lockstep -> every wave ds_reads at once, then every wave MFMAs
// at once; the LDS and MFMA pipes alternated instead of co-running (the
// additive 931+768 cyc/tap cost measured R12..R15). Waves 4..7 (SIMD
// partners of 0..3, wave->SIMD = wave%4) start at tap 4 (mod 9): on each
// SIMD one wave MFMAs while its partner reads LDS, and they swap. Same
// LDS buffers, same barriers; only within-chunk tap order differs (exact
// for BIN ints; ulp-level fp32 reorder for real, tol 4e-3).

typedef unsigned short u16;
typedef __attribute__((ext_vector_type(8))) short short8;
typedef __attribute__((ext_vector_type(8))) unsigned short ushort8;
typedef __attribute__((ext_vector_type(4))) unsigned short ushort4v;
typedef __attribute__((ext_vector_type(4))) float float4v;

__device__ __forceinline__ float bf2f(u16 u) { return __uint_as_float(((unsigned)u) << 16); }
__device__ __forceinline__ u16 f2bf(float f) {
    unsigned u = __float_as_uint(f);
    return (u16)((u + 0x7FFFu + ((u >> 16) & 1u)) >> 16);
}
__device__ __forceinline__ u16 lo_bf(float y, u16 hi) {  // bf16(y - fl(hi))
    return f2bf(y - bf2f(hi));
}
__device__ __forceinline__ u16 signbf(float y) {
    return y > 0.f ? 0x3F80u : (y < 0.f ? 0xBF80u : 0u);
}

// ---------------- conv0_main: 3->128, 32x32, direct fp32, fp32 NHWC out ----------------
__global__ __launch_bounds__(256) void conv0_main(const float* __restrict__ x,
                                                  const float* __restrict__ w0,
                                                  float* __restrict__ out) {
    __shared__ float xt[306];     // [ci][kh][w+2pad], 34-stride rows
    __shared__ float wl[3456];    // 128*27
    const int t = threadIdx.x;
    const int n = blockIdx.x >> 5;
    const int h = blockIdx.x & 31;
    for (int i = t; i < 306; i += 256) xt[i] = 0.f;
    for (int i = t; i < 3456; i += 256) wl[i] = w0[i];
    __syncthreads();
    for (int i = t; i < 288; i += 256) {
        int ci = i / 96; int rr = (i / 32) % 3; int w = i & 31;
        int gh = h - 1 + rr;
        if (gh >= 0 && gh < 32)
            xt[(ci * 3 + rr) * 34 + w + 1] = x[((n * 3 + ci) * 32 + gh) * 32 + w];
    }
    __syncthreads();
    const int w = t & 31, cg = t >> 5;
    float xin[27];
#pragma unroll
    for (int ci = 0; ci < 3; ci++)
#pragma unroll
        for (int r = 0; r < 3; r++)
#pragma unroll
            for (int kw = 0; kw < 3; kw++)
                xin[(ci * 3 + r) * 3 + kw] = xt[(ci * 3 + r) * 34 + w + kw];
    float* o = out + ((size_t)(n * 1024 + h * 32 + w)) * 128 + cg * 16;
#pragma unroll
    for (int jq = 0; jq < 4; jq++) {
        float4v v;
#pragma unroll
        for (int jk = 0; jk < 4; jk++) {
            int co = cg * 16 + jq * 4 + jk;
            float a = 0.f;
#pragma unroll
            for (int e = 0; e < 27; e++) a += xin[e] * wl[co * 27 + e];
            v[jk] = a;
        }
        *(float4v*)(o + jq * 4) = v;
    }
}

// ---------------- stats over fp32 NHWC (stage 0) ----------------
__global__ __launch_bounds__(256) void stats0_kernel(const float* __restrict__ src,
                                                     float* __restrict__ st,
                                                     int C, int rows_per_block) {
    const int t = threadIdx.x;
    const int c = blockIdx.x * 64 + (t & 63);
    const int rg = t >> 6;
    const int r0 = blockIdx.y * rows_per_block;
    float s = 0.f, q = 0.f;
    for (int r = r0 + rg; r < r0 + rows_per_block; r += 4) {
        float v = src[(size_t)r * C + c];
        s += v;
        q += v * v;
    }
    __shared__ float Ls[256], Lq[256];
    Ls[t] = s; Lq[t] = q;
    __syncthreads();
    if (t < 64) {
        s = Ls[t] + Ls[t + 64] + Ls[t + 128] + Ls[t + 192];
        q = Lq[t] + Lq[t + 64] + Lq[t + 128] + Lq[t + 192];
        atomicAdd(&st[c], s);
        atomicAdd(&st[C + c], q);
    }
}

// ---------------- bn0_apply: fp32 conv0-out -> sign acts + real hi/lo acts ----------------
__global__ __launch_bounds__(256) void bn0_apply(const float* __restrict__ src,
                                                 const float* __restrict__ st,
                                                 const float* __restrict__ g,
                                                 const float* __restrict__ b,
                                                 u16* __restrict__ sg,
                                                 u16* __restrict__ hi,
                                                 u16* __restrict__ lo) {
    const int t = threadIdx.x;
    __shared__ float sc[128], sh[128];
    if (t < 128) {
        float mean = st[t] * (1.f / 131072.f);
        float var = fmaxf(st[128 + t] * (1.f / 131072.f) - mean * mean, 0.f);
        float scale = rsqrtf(var + 1e-5f) * g[t];
        sc[t] = scale;
        sh[t] = b[t] - mean * scale;
    }
    __syncthreads();
    size_t i = ((size_t)blockIdx.x * 256 + t) * 4;
    int c0 = (int)(i & 127);
    float4v v = *(const float4v*)(src + i);
    ushort4v hv, lv, sv;
#pragma unroll
    for (int k = 0; k < 4; k++) {
        float y = fminf(fmaxf(v[k] * sc[c0 + k] + sh[c0 + k], -1.f), 1.f);
        hv[k] = f2bf(y);
        lv[k] = lo_bf(y, hv[k]);
        sv[k] = signbf(y);
    }
    *(ushort4v*)(sg + i) = sv;
    *(ushort4v*)(hi + i) = hv;
    *(ushort4v*)(lo + i) = lv;
}

// ---------------- weight prepack; BIN = standardize+sign, else hi+lo split ----------------
template <bool BIN>
__global__ __launch_bounds__(256) void prepack_kernel(const float* __restrict__ w,
                                                      u16* __restrict__ apk,
                                                      u16* __restrict__ apkLo,
                                                      int Cin, int Cout) {
    const int t = threadIdx.x, o = blockIdx.x;
    const int E = Cin * 9;
    float m = 0.f;
    if (BIN) {
        float s = 0.f;
        for (int e = t; e < E; e += 256) s += w[o * E + e];
        __shared__ float Ls[256];
        Ls[t] = s;
        __syncthreads();
        for (int stp = 128; stp > 0; stp >>= 1) {
            if (t < stp) Ls[t] += Ls[t + stp];
            __syncthreads();
        }
        m = Ls[0] / (float)E;
    }
    const int CC = Cin >> 5, COT = Cout >> 7;
    for (int e = t; e < E; e += 256) {
        int ci = e / 9, tap = e % 9;
        float raw = w[o * E + e];
        int idx = ((tap * CC + (ci >> 5)) * COT + (o >> 7)) * 4096 + (o & 127) * 32 + (ci & 31);
        if (BIN) {
            apk[idx] = signbf(raw - m);
        } else {
            u16 hi = f2bf(raw);
            apk[idx] = hi;
            apkLo[idx] = lo_bf(raw, hi);
        }
    }
}

// ---------------- implicit-GEMM MFMA conv (8 waves / 512 threads) ----------------
// R15 structure + anti-phase tap rotation: waves 4..7 start at tap 4.
// Waves: wm = wave>>1 (32 co rows, acc[2][4]); wn = wave&1 (64 cols).
// A direct from prepacked global (ping-pong); B reg ping-pong from dbuf
// LDS; per-tap sched_barrier(0) fence + setprio around the MFMA cluster.
template <bool POOL, bool BIN>
__global__ __launch_bounds__(512, 2) void conv_mfma_kernel(
    const u16* __restrict__ act, const u16* __restrict__ actLo,
    const u16* __restrict__ apk, const u16* __restrict__ apkLo,
    u16* __restrict__ out, u16* __restrict__ outLo,
    int Cin, int Cout, int H, int W) {
    const int HW = H * W;
    const int t = threadIdx.x;
    const int wave = t >> 6, lane = t & 63;
    const int l15 = lane & 15, quad = lane >> 4;
    const int wm = wave >> 1, wn = wave & 1;   // wm 0..3 (32 co rows each)
    // anti-phase: SIMD partner waves (0..3 vs 4..7) start 4 taps apart
    const int trot = ((wave >> 2) & 1) * 4;

    const int col0 = blockIdx.x * 128;
    const int cot = blockIdx.y;
    const int CC = Cin >> 5;
    const int COT = Cout >> 7;
    const bool two = (HW < 128);          // 128 cols span two images (HW==64)
    const int Wp = W + 2;
    const int nrows = two ? 2 * (H + 2) : (128 / W + 2);
    const int n0 = col0 / HW;
    const int h0 = two ? 0 : (col0 % HW) / W;

    __shared__ __align__(16) u16 BsH[2][8160];                       // dbuf [cell][40]
    __shared__ __align__(16) u16 BsL[BIN ? 1 : 2][BIN ? 16 : 8160];

    int bbase[4], gcol[4];
#pragma unroll
    for (int ni = 0; ni < 4; ni++) {
        int c = wn * 64 + ni * 16 + l15;
        int g = col0 + c;
        int n = g / HW; int hw = g % HW; int h = hw / W; int w = hw % W;
        gcol[ni] = g;
        int rb = two ? ((n - n0) * (H + 2) + h) : (h - h0);
        bbase[ni] = (rb * Wp + w) * 40 + quad * 8;
    }
    // first-tap B offset for this wave's rotated sequence
    const int boff0 = ((trot / 3) * Wp + (trot % 3)) * 40;

    // ---- hoisted B-staging address math (cc-invariant) ----
    const int bgroups = nrows * Wp * 4;   // <= 1024 for all stages
    int svalid[2]; size_t sgoff[2]; int sloff[2];
#pragma unroll
    for (int j = 0; j < 2; j++) {
        int idx = t + j * 512;
        svalid[j] = 0; sgoff[j] = 0; sloff[j] = 0;
        if (idx < bgroups) {
            int cig = idx & 3;
            int rest = idx >> 2;
            int wp = rest % Wp;
            int srow = rest / Wp;
            int n, gh;
            if (two) { n = n0 + srow / (H + 2); gh = srow % (H + 2) - 1; }
            else     { n = n0; gh = h0 + srow - 1; }
            int gw = wp - 1;
            sloff[j] = (srow * Wp + wp) * 40 + cig * 8;
            if (gh >= 0 && gh < H && gw >= 0 && gw < W) {
                svalid[j] = 2;
                sgoff[j] = ((size_t)(n * HW + gh * W + gw)) * Cin + cig * 8;
            } else {
                svalid[j] = 1;   // in-range LDS cell, zero fill
            }
        }
    }

    float4v acc[2][4];
    const float4v zf = {0.f, 0.f, 0.f, 0.f};
#pragma unroll
    for (int mi = 0; mi < 2; mi++)
#pragma unroll
        for (int ni = 0; ni < 4; ni++) acc[mi][ni] = zf;

    const size_t tapstride = (size_t)CC * COT * 4096;
    // A-fragment offset within a tap tile: (wm*32 + l15) rows of 32 ci
    const int arow0 = wm * 1024 + l15 * 32 + quad * 8;

    short8 ahP[2][2];                     // ping-pong A-hi frags
    short8 alP[2][2];                     // ping-pong A-lo frags (real only)
    short8 ah0N[2], al0N[2];              // cross-chunk first-tap A prefetch
    short8 bhP[2][4];                     // ping-pong B-hi frags
    short8 blP[2][4];                     // ping-pong B-lo frags (real only)
    short8 svh[2], svl[2];                // reg-staged B for next chunk
    const short8 z8 = {0, 0, 0, 0, 0, 0, 0, 0};

    // ---- prologue: stage chunk 0 into buf 0, load first-tap A, then first-tap B frags ----
    {
        const u16* ab0 = apk + ((size_t)cot) * 4096 + (size_t)trot * tapstride;
        const u16* ab0L = apkLo + ((size_t)cot) * 4096 + (size_t)trot * tapstride;
#pragma unroll
        for (int mi = 0; mi < 2; mi++) {
            ahP[0][mi] = *(const short8*)(ab0 + arow0 + mi * 512);
            if (!BIN) alP[0][mi] = *(const short8*)(ab0L + arow0 + mi * 512);
        }
#pragma unroll
        for (int j = 0; j < 2; j++) {
            svh[j] = z8; svl[j] = z8;
            if (svalid[j] == 2) {
                svh[j] = *(const short8*)(act + sgoff[j]);
                if (!BIN) svl[j] = *(const short8*)(actLo + sgoff[j]);
            }
        }
#pragma unroll
        for (int j = 0; j < 2; j++) {
            if (svalid[j]) {
                *(short8*)&BsH[0][sloff[j]] = svh[j];
                if (!BIN) *(short8*)&BsL[0][sloff[j]] = svl[j];
            }
        }
        __syncthreads();
        // first-tap B fragments (rotated)
#pragma unroll
        for (int ni = 0; ni < 4; ni++) {
            bhP[0][ni] = *(const short8*)&BsH[0][bbase[ni] + boff0];
            if (!BIN) blP[0][ni] = *(const short8*)&BsL[0][bbase[ni] + boff0];
        }
    }

    for (int cc = 0; cc < CC; cc++) {
        const int cur = cc & 1, nx = cur ^ 1;
        const bool more = (cc + 1 < CC);
        const u16* ab = apk + ((size_t)(cc * COT + cot)) * 4096;
        const u16* abL = apkLo + ((size_t)(cc * COT + cot)) * 4096;

        // issue next chunk's B global loads + first-tap A loads (consumed after taps)
        if (more) {
            const size_t ccb = (size_t)(cc + 1) * 32;
#pragma unroll
            for (int j = 0; j < 2; j++) {
                svh[j] = z8; svl[j] = z8;
                if (svalid[j] == 2) {
                    svh[j] = *(const short8*)(act + sgoff[j] + ccb);
                    if (!BIN) svl[j] = *(const short8*)(actLo + sgoff[j] + ccb);
                }
            }
            const u16* abN = apk + ((size_t)((cc + 1) * COT + cot)) * 4096 + (size_t)trot * tapstride;
            const u16* abNL = apkLo + ((size_t)((cc + 1) * COT + cot)) * 4096 + (size_t)trot * tapstride;
#pragma unroll
            for (int mi = 0; mi < 2; mi++) {
                ah0N[mi] = *(const short8*)(abN + arow0 + mi * 512);
                if (!BIN) al0N[mi] = *(const short8*)(abNL + arow0 + mi * 512);
            }
        }

#pragma unroll
        for (int tap = 0; tap < 9; tap++) {
            const int curp = tap & 1, nxp = curp ^ 1;
            if (tap < 8) {
                // rotated next tap
                int tpn = tap + 1 + trot; if (tpn >= 9) tpn -= 9;
                // A prefetch (global, L1-resident)
                const u16* at = ab + (size_t)tpn * tapstride;
#pragma unroll
                for (int mi = 0; mi < 2; mi++)
                    ahP[nxp][mi] = *(const short8*)(at + arow0 + mi * 512);
                if (!BIN) {
                    const u16* atL = abL + (size_t)tpn * tapstride;
#pragma unroll
                    for (int mi = 0; mi < 2; mi++)
                        alP[nxp][mi] = *(const short8*)(atL + arow0 + mi * 512);
                }
                // B prefetch (LDS)
                const int boff1 = ((tpn / 3) * Wp + (tpn % 3)) * 40;
#pragma unroll
                for (int ni = 0; ni < 4; ni++) {
                    bhP[nxp][ni] = *(const short8*)&BsH[cur][bbase[ni] + boff1];
                    if (!BIN) blP[nxp][ni] = *(const short8*)&BsL[cur][bbase[ni] + boff1];
                }
            }
            // hard fence: prefetch issues above cannot sink below; MFMAs
            // below cannot hoist above.
            __builtin_amdgcn_sched_barrier(0);
            __builtin_amdgcn_s_setprio(1);
            if (BIN) {
#pragma unroll
                for (int mi = 0; mi < 2; mi++)
#pragma unroll
                    for (int ni = 0; ni < 4; ni++)
                        acc[mi][ni] = __builtin_amdgcn_mfma_f32_16x16x32_bf16(
                            ahP[curp][mi], bhP[curp][ni], acc[mi][ni], 0, 0, 0);
            } else {
                // three 8-MFMA sweeps: each acc has dep distance 8
#pragma unroll
                for (int mi = 0; mi < 2; mi++)
#pragma unroll
                    for (int ni = 0; ni < 4; ni++)
                        acc[mi][ni] = __builtin_amdgcn_mfma_f32_16x16x32_bf16(
                            ahP[curp][mi], bhP[curp][ni], acc[mi][ni], 0, 0, 0);
#pragma unroll
                for (int mi = 0; mi < 2; mi++)
#pragma unroll
                    for (int ni = 0; ni < 4; ni++)
                        acc[mi][ni] = __builtin_amdgcn_mfma_f32_16x16x32_bf16(
                            ahP[curp][mi], blP[curp][ni], acc[mi][ni], 0, 0, 0);
#pragma unroll
                for (int mi = 0; mi < 2; mi++)
#pragma unroll
                    for (int ni = 0; ni < 4; ni++)
                        acc[mi][ni] = __builtin_amdgcn_mfma_f32_16x16x32_bf16(
                            alP[curp][mi], bhP[curp][ni], acc[mi][ni], 0, 0, 0);
            }
            __builtin_amdgcn_s_setprio(0);
        }

        if (more) {
            // write staged B into the other buffer, then one barrier
#pragma unroll
            for (int j = 0; j < 2; j++) {
                if (svalid[j]) {
                    *(short8*)&BsH[nx][sloff[j]] = svh[j];
                    if (!BIN) *(short8*)&BsL[nx][sloff[j]] = svl[j];
                }
            }
            __syncthreads();
            // install prefetched first-tap A and load first-tap B frags for next chunk
#pragma unroll
            for (int mi = 0; mi < 2; mi++) {
                ahP[0][mi] = ah0N[mi];
                if (!BIN) alP[0][mi] = al0N[mi];
            }
#pragma unroll
            for (int ni = 0; ni < 4; ni++) {
                bhP[0][ni] = *(const short8*)&BsH[nx][bbase[ni] + boff0];
                if (!BIN) blP[0][ni] = *(const short8*)&BsL[nx][bbase[ni] + boff0];
            }
        }
    }

    const int cobase = cot * 128 + wm * 32 + quad * 4;
    // store helper: BIN -> int16 exact; real -> bf16 hi + bf16 lo
    auto store4 = [&](size_t off, float4v v) {
        if (BIN) {
            ushort4v r;
#pragma unroll
            for (int k = 0; k < 4; k++) r[k] = (u16)(short)(int)v[k];
            *(ushort4v*)(out + off) = r;
        } else {
            ushort4v hi, lo;
#pragma unroll
            for (int k = 0; k < 4; k++) {
                hi[k] = f2bf(v[k]);
                lo[k] = lo_bf(v[k], hi[k]);
            }
            *(ushort4v*)(out + off) = hi;
            *(ushort4v*)(outLo + off) = lo;
        }
    };

    if (!POOL) {
#pragma unroll
        for (int mi = 0; mi < 2; mi++)
#pragma unroll
            for (int ni = 0; ni < 4; ni++)
                store4((size_t)gcol[ni] * Cout + cobase + mi * 16, acc[mi][ni]);
    } else {
        const int pH = H >> 1, pW = W >> 1;
        if (W == 32) {
#pragma unroll
            for (int mi = 0; mi < 2; mi++)
#pragma unroll
                for (int nip = 0; nip < 2; nip++) {
                    float4v v;
#pragma unroll
                    for (int k = 0; k < 4; k++)
                        v[k] = fmaxf((float)acc[mi][nip][k], (float)acc[mi][nip + 2][k]);
#pragma unroll
                    for (int k = 0; k < 4; k++) {
                        float vv = v[k];
                        v[k] = fmaxf(vv, __shfl_xor(vv, 1, 64));
                    }
                    if ((l15 & 1) == 0) {
                        int pw = nip * 8 + (l15 >> 1);
                        int ph = (h0 >> 1) + wn;
                        int prow = (n0 * pH + ph) * pW + pw;
                        store4((size_t)prow * Cout + cobase + mi * 16, v);
                    }
                }
        } else if (W == 16) {
#pragma unroll
            for (int mi = 0; mi < 2; mi++)
#pragma unroll
                for (int nip = 0; nip < 4; nip += 2) {
                    float4v v;
#pragma unroll
                    for (int k = 0; k < 4; k++)
                        v[k] = fmaxf((float)acc[mi][nip][k], (float)acc[mi][nip + 1][k]);
#pragma unroll
                    for (int k = 0; k < 4; k++) {
                        float vv = v[k];
                        v[k] = fmaxf(vv, __shfl_xor(vv, 1, 64));
                    }
                    if ((l15 & 1) == 0) {
                        int pw = l15 >> 1;
                        int ph = (h0 + wn * 4 + nip) >> 1;
                        int prow = (n0 * pH + ph) * pW + pw;
                        store4((size_t)prow * Cout + cobase + mi * 16, v);
                    }
                }
        } else {  // W == 8, two-image: n = n0 + wn, h = ni*2 + (l15>>3), w = l15&7
#pragma unroll
            for (int mi = 0; mi < 2; mi++)
#pragma unroll
                for (int ni = 0; ni < 4; ni++) {
                    float4v v = acc[mi][ni];
#pragma unroll
                    for (int k = 0; k < 4; k++) {
                        float vv = v[k];
                        vv = fmaxf(vv, __shfl_xor(vv, 1, 64));
                        v[k] = fmaxf(vv, __shfl_xor(vv, 8, 64));
                    }
                    if ((l15 & 9) == 0) {
                        int pw = l15 >> 1;
                        int ph = ni;
                        int n = n0 + wn;
                        int prow = (n * pH + ph) * pW + pw;
                        store4((size_t)prow * Cout + cobase + mi * 16, v);
                    }
                }
        }
    }
}

// ---------------- per-channel batch stats (sum, sumsq); BIN=int16, real=hi+lo ----------------
template <bool BIN>
__global__ __launch_bounds__(256) void stats_kernel(const u16* __restrict__ src,
                                                    const u16* __restrict__ srcLo,
                                                    float* __restrict__ st,
                                                    int C, int rows_per_block) {
    const int t = threadIdx.x;
    const int c = blockIdx.x * 64 + (t & 63);
    const int rg = t >> 6;
    const int r0 = blockIdx.y * rows_per_block;
    float s = 0.f, q = 0.f;
    for (int r = r0 + rg; r < r0 + rows_per_block; r += 4) {
        size_t i = (size_t)r * C + c;
        float v = BIN ? (float)(short)src[i] : (bf2f(src[i]) + bf2f(srcLo[i]));
        s += v;
        q += v * v;
    }
    __shared__ float Ls[256], Lq[256];
    Ls[t] = s; Lq[t] = q;
    __syncthreads();
    if (t < 64) {
        s = Ls[t] + Ls[t + 64] + Ls[t + 128] + Ls[t + 192];
        q = Lq[t] + Lq[t + 64] + Lq[t + 128] + Lq[t + 192];
        atomicAdd(&st[c], s);
        atomicAdd(&st[C + c], q);
    }
}

// ---------------- BN + hardtanh; acts (mode 1=real hi+lo, 2=sign) + fp32 NCHW d_out ----------------
template <bool BIN>
__global__ __launch_bounds__(256) void bn_apply_kernel(const u16* __restrict__ src,
                                                       const u16* __restrict__ srcLo,
                                                       int C, int HW,
                                                       const float* __restrict__ st, float cntinv,
                                                       const float* __restrict__ g,
                                                       const float* __restrict__ b,
                                                       float* __restrict__ dout,
                                                       float* __restrict__ dout2,
                                                       u16* __restrict__ act,
                                                       u16* __restrict__ actLo,
                                                       int act_mode) {
    const int t = threadIdx.x;
    const int cl = t & 63, rl = t >> 6;
    const int c = blockIdx.y * 64 + cl;
    const float mean = st[c] * cntinv;
    float var = st[C + c] * cntinv - mean * mean;
    var = fmaxf(var, 0.f);
    const float scale = rsqrtf(var + 1e-5f) * g[c];
    const float shift = b[c] - mean * scale;
    __shared__ float T[64][65];
#pragma unroll
    for (int i = 0; i < 16; i++) {
        int rlocal = rl + i * 4;
        int row = blockIdx.x * 64 + rlocal;
        size_t idx = (size_t)row * C + c;
        float v = BIN ? (float)(short)src[idx] : (bf2f(src[idx]) + bf2f(srcLo[idx]));
        float y = fminf(fmaxf(v * scale + shift, -1.f), 1.f);
        if (act_mode == 1) {
            u16 hi = f2bf(y);
            act[idx] = hi;
            actLo[idx] = lo_bf(y, hi);
        } else if (act_mode == 2) {
            act[idx] = signbf(y);
        }
        T[rlocal][cl] = y;
    }
    __syncthreads();
#pragma unroll
    for (int i = 0; i < 16; i++) {
        int clocal = rl + i * 4;
        int cg = blockIdx.y * 64 + clocal;
        int rglob = blockIdx.x * 64 + cl;
        int n = rglob / HW, hw = rglob % HW;
        size_t o = ((size_t)n * C + cg) * HW + hw;
        float val = T[cl][clocal];
        dout[o] = val;
        if (dout2) dout2[o] = val;
    }
}

// ---------------- FC: [128,8192] @ [10,8192]^T + b (all fp32) ----------------
__global__ __launch_bounds__(256) void fc_kernel(const float* __restrict__ penul,
                                                 const float* __restrict__ fcw,
                                                 const float* __restrict__ fcb,
                                                 float* __restrict__ out) {
    const int t = threadIdx.x, n = blockIdx.x;
    float acc[10];
#pragma unroll
    for (int j = 0; j < 10; j++) acc[j] = 0.f;
    for (int i = t; i < 8192; i += 256) {
        float p = penul[n * 8192 + i];
#pragma unroll
        for (int j = 0; j < 10; j++) acc[j] += p * fcw[j * 8192 + i];
    }
    __shared__ float L[10][256];
#pragma unroll
    for (int j = 0; j < 10; j++) L[j][t] = acc[j];
    __syncthreads();
    for (int s = 128; s > 0; s >>= 1) {
        if (t < s) {
#pragma unroll
            for (int j = 0; j < 10; j++) L[j][t] += L[j][t + s];
        }
        __syncthreads();
    }
    if (t < 10) out[n * 10 + t] = L[t][0] + fcb[t];
}

extern "C" void kernel_launch(void* const* d_in, const int* in_sizes, int n_in,
                              void* d_out, int out_size, void* d_ws, size_t ws_size,
                              hipStream_t stream) {
    (void)in_sizes; (void)n_in; (void)out_size; (void)ws_size;

    const float* X = (const float*)d_in[0];
    const float* W0 = (const float*)d_in[1];
    const float* Wl[5] = {(const float*)d_in[2], (const float*)d_in[3], (const float*)d_in[4],
                          (const float*)d_in[5], (const float*)d_in[6]};
    const float* FCW = (const float*)d_in[7];
    const float* FCB = (const float*)d_in[8];
    const float* G[6]; const float* Bb[6];
    for (int i = 0; i < 6; i++) { G[i] = (const float*)d_in[9 + 2 * i]; Bb[i] = (const float*)d_in[10 + 2 * i]; }

    float* OUT = (float*)d_out;
    char* ws = (char*)d_ws;

    // ws layout (bytes), all disjoint, total 93,329,408 (R6-proven):
    u16* apk   = (u16*)(ws);               // [0,          4,718,592)
    u16* apkLo = (u16*)(ws + 4718592);     // [4,718,592,  9,437,184)
    float* st0 = (float*)(ws + 9437184);   // [9,437,184,  9,439,232)
    float* stk = (float*)(ws + 9439232);   // [9,439,232,  9,443,328)
    u16* F     = (u16*)(ws + 9443328);     // 8,388,608 elems (hi / int16)
    u16* Flo   = (u16*)(ws + 26220544);    // 8,388,608 elems (lo, real)
    u16* AB    = (u16*)(ws + 42997760);    // 8,388,608 elems
    u16* AR    = (u16*)(ws + 59774976);    // 8,388,608 elems
    u16* ARlo  = (u16*)(ws + 76552192);    // 8,388,608 elems

    // Stage-0 arenas: C0 in ws (F..AR range, dead until stage 1); sign acts SG
    // and real hi/lo acts in dead d_out regions (R8-proven lifetimes).
    float* C0 = (float*)(ws + 9443328);
    u16* SG   = (u16*)(OUT + 26215680);
    u16* X0   = (u16*)(OUT + 9438464);
    u16* X0lo = (u16*)(OUT + 17827072);

    float* O_out = OUT;
    float* O_pen = OUT + 1280;
    float* O_L1b = OUT + 1049856;
    float* O_L1r = OUT + 5244160;
    float* O_L2b = OUT + 9438464;
    float* O_L2r = OUT + 17827072;
    float* O_L3b = OUT + 26215680;
    float* O_L3r = OUT + 28312832;
    float* O_L4b = OUT + 30409984;
    float* O_L4r = OUT + 34604288;
    float* O_L5b = OUT + 38798592;
    float* O_L5r = OUT + 39847168;

    // ---- stage 0: conv0 (1 pass, fp32 -> ws) -> stats -> bn apply (sign + hi/lo)
    conv0_main<<<4096, 256, 0, stream>>>(X, W0, C0);
    hipMemsetAsync(st0, 0, 2048, stream);
    stats0_kernel<<<dim3(2, 256), 256, 0, stream>>>(C0, st0, 128, 512);
    bn0_apply<<<16384, 256, 0, stream>>>(C0, st0, G[0], Bb[0], SG, X0, X0lo);

    struct Stage {
        const float* w; int Cin, Cout, H, W; bool pool;
        dim3 cgrid; dim3 sgrid; int srpb; dim3 bgrid; int bHW; float cntinv;
        float* db; float* dr;
    };
    const Stage S[5] = {
        {Wl[0], 128, 128, 32, 32, true,  dim3(1024, 1), dim3(2, 64), 512, dim3(512, 2), 256, 1.f / 32768.f, O_L1b, O_L1r},
        {Wl[1], 128, 256, 16, 16, false, dim3(256, 2),  dim3(4, 64), 512, dim3(512, 4), 256, 1.f / 32768.f, O_L2b, O_L2r},
        {Wl[2], 256, 256, 16, 16, true,  dim3(256, 2),  dim3(4, 16), 512, dim3(128, 4), 64,  1.f / 8192.f,  O_L3b, O_L3r},
        {Wl[3], 256, 512, 8, 8,   false, dim3(64, 4),   dim3(8, 16), 512, dim3(128, 8), 64,  1.f / 8192.f,  O_L4b, O_L4r},
        {Wl[4], 512, 512, 8, 8,   true,  dim3(64, 4),   dim3(8, 16), 128, dim3(32, 8),  16,  1.f / 2048.f,  O_L5b, O_L5r},
    };

    for (int k = 0; k < 5; k++) {
        const Stage& s = S[k];
        const u16* inB = (k == 0) ? SG : AB;
        const u16* inR = (k == 0) ? X0 : AR;
        const u16* inRlo = (k == 0) ? X0lo : ARlo;

        // ---- binary branch (exact: sign weights/acts, int16 conv-out)
        prepack_kernel<true><<<s.Cout, 256, 0, stream>>>(s.w, apk, nullptr, s.Cin, s.Cout);
        if (s.pool) conv_mfma_kernel<true, true><<<s.cgrid, 512, 0, stream>>>(inB, nullptr, apk, apk, F, nullptr, s.Cin, s.Cout, s.H, s.W);
        else        conv_mfma_kernel<false, true><<<s.cgrid, 512, 0, stream>>>(inB, nullptr, apk, apk, F, nullptr, s.Cin, s.Cout, s.H, s.W);
        hipMemsetAsync(stk, 0, 4096, stream);
        stats_kernel<true><<<s.sgrid, 256, 0, stream>>>(F, nullptr, stk, s.Cout, s.srpb);
        bn_apply_kernel<true><<<s.bgrid, 256, 0, stream>>>(F, nullptr, s.Cout, s.bHW, stk, s.cntinv,
                                                           G[k + 1], Bb[k + 1], s.db,
                                                           (k == 4) ? O_pen : nullptr,
                                                           AB, nullptr, (k == 4) ? 0 : 2);

        // ---- real branch (single traversal, 3-term split-bf16; out hi+lo)
        prepack_kernel<false><<<s.Cout, 256, 0, stream>>>(s.w, apk, apkLo, s.Cin, s.Cout);
        if (s.pool) conv_mfma_kernel<true, false><<<s.cgrid, 512, 0, stream>>>(inR, inRlo, apk, apkLo, F, Flo, s.Cin, s.Cout, s.H, s.W);
        else        conv_mfma_kernel<false, false><<<s.cgrid, 512, 0, stream>>>(inR, inRlo, apk, apkLo, F, Flo, s.Cin, s.Cout, s.H, s.W);
        hipMemsetAsync(stk, 0, 4096, stream);
        stats_kernel<false><<<s.sgrid, 256, 0, stream>>>(F, Flo, stk, s.Cout, s.srpb);
        bn_apply_kernel<false><<<s.bgrid, 256, 0, stream>>>(F, Flo, s.Cout, s.bHW, stk, s.cntinv,
                                                            G[k + 1], Bb[k + 1], s.dr, nullptr,
                                                            AR, ARlo, (k == 4) ? 0 : 1);
    }

    // ---- fc
    fc_kernel<<<128, 256, 0, stream>>>(O_pen, FCW, FCB, O_out);
}

// Round 9
// 1191.162 us; speedup vs baseline: 1.4467x; 1.1907x over previous
//
#include <hip/hip_runtime.h>

// VGG_SMALL_1W1A on MI355X — R18.
// R17 (anti-phase tap rotation) neutral-negative: 115.2 us top dispatch,
// VALUBusy 23->27 (mod-9 addr math), total 1418. Reverted to R15.
// Evidence after 6 structural variants (R12..R17 all 113-115 us, MfmaUtil
// ~44%, SQ_LDS_BANK_CONFLICT constant 1.027e7 = benign 2-way aliasing):
// this conv loop is at its structural ceiling. The remaining ~650 us of
// the 1381 total is in ~45 small dispatches: 11 stats kernels re-reading
// 16-67MB just written by conv, 11 memsets, and dispatch gaps.
// R18: FUSE stats into conv/conv0 epilogues. Each thread shfl-reduces
// (sum,sumsq) over its 16 column lanes (channels are l15-invariant),
// LDS-atomicAdd into a 128-ch block accumulator, one global atomicAdd per
// thread (<=1024 adds/address ~ 2us tail). Real stats use fp32 acc (closer
// to exact reference than quantized hi+lo). stk zeroing moved into
// prepack block 0. Removes 21 dispatches + ~150MB re-reads.

typedef unsigned short u16;
typedef __attribute__((ext_vector_type(8))) short short8;
typedef __attribute__((ext_vector_type(8))) unsigned short ushort8;
typedef __attribute__((ext_vector_type(4))) unsigned short ushort4v;
typedef __attribute__((ext_vector_type(4))) float float4v;

__device__ __forceinline__ float bf2f(u16 u) { return __uint_as_float(((unsigned)u) << 16); }
__device__ __forceinline__ u16 f2bf(float f) {
    unsigned u = __float_as_uint(f);
    return (u16)((u + 0x7FFFu + ((u >> 16) & 1u)) >> 16);
}
__device__ __forceinline__ u16 lo_bf(float y, u16 hi) {  // bf16(y - fl(hi))
    return f2bf(y - bf2f(hi));
}
__device__ __forceinline__ u16 signbf(float y) {
    return y > 0.f ? 0x3F80u : (y < 0.f ? 0xBF80u : 0u);
}

// ---------------- conv0_main: 3->128, 32x32, direct fp32, fp32 NHWC out + fused stats ----------------
__global__ __launch_bounds__(256) void conv0_main(const float* __restrict__ x,
                                                  const float* __restrict__ w0,
                                                  float* __restrict__ out,
                                                  float* __restrict__ st0) {
    __shared__ float xt[306];     // [ci][kh][w+2pad], 34-stride rows
    __shared__ float wl[3456];    // 128*27
    __shared__ float S0[128], Q0[128];
    const int t = threadIdx.x;
    const int n = blockIdx.x >> 5;
    const int h = blockIdx.x & 31;
    for (int i = t; i < 306; i += 256) xt[i] = 0.f;
    for (int i = t; i < 3456; i += 256) wl[i] = w0[i];
    if (t < 128) { S0[t] = 0.f; Q0[t] = 0.f; }
    __syncthreads();
    for (int i = t; i < 288; i += 256) {
        int ci = i / 96; int rr = (i / 32) % 3; int w = i & 31;
        int gh = h - 1 + rr;
        if (gh >= 0 && gh < 32)
            xt[(ci * 3 + rr) * 34 + w + 1] = x[((n * 3 + ci) * 32 + gh) * 32 + w];
    }
    __syncthreads();
    const int w = t & 31, cg = t >> 5;
    float xin[27];
#pragma unroll
    for (int ci = 0; ci < 3; ci++)
#pragma unroll
        for (int r = 0; r < 3; r++)
#pragma unroll
            for (int kw = 0; kw < 3; kw++)
                xin[(ci * 3 + r) * 3 + kw] = xt[(ci * 3 + r) * 34 + w + kw];
    float* o = out + ((size_t)(n * 1024 + h * 32 + w)) * 128 + cg * 16;
#pragma unroll
    for (int jq = 0; jq < 4; jq++) {
        float4v v;
#pragma unroll
        for (int jk = 0; jk < 4; jk++) {
            int co = cg * 16 + jq * 4 + jk;
            float a = 0.f;
#pragma unroll
            for (int e = 0; e < 27; e++) a += xin[e] * wl[co * 27 + e];
            v[jk] = a;
        }
        *(float4v*)(o + jq * 4) = v;
        // fused stats: reduce over the 32 w-lanes (channel is w-invariant)
#pragma unroll
        for (int jk = 0; jk < 4; jk++) {
            float s = v[jk], q = v[jk] * v[jk];
            s += __shfl_xor(s, 1, 64);  q += __shfl_xor(q, 1, 64);
            s += __shfl_xor(s, 2, 64);  q += __shfl_xor(q, 2, 64);
            s += __shfl_xor(s, 4, 64);  q += __shfl_xor(q, 4, 64);
            s += __shfl_xor(s, 8, 64);  q += __shfl_xor(q, 8, 64);
            s += __shfl_xor(s, 16, 64); q += __shfl_xor(q, 16, 64);
            if ((t & 31) == 0) {
                atomicAdd(&S0[cg * 16 + jq * 4 + jk], s);
                atomicAdd(&Q0[cg * 16 + jq * 4 + jk], q);
            }
        }
    }
    __syncthreads();
    if (t < 128) {
        atomicAdd(&st0[t], S0[t]);
        atomicAdd(&st0[128 + t], Q0[t]);
    }
}

// ---------------- bn0_apply: fp32 conv0-out -> sign acts + real hi/lo acts ----------------
__global__ __launch_bounds__(256) void bn0_apply(const float* __restrict__ src,
                                                 const float* __restrict__ st,
                                                 const float* __restrict__ g,
                                                 const float* __restrict__ b,
                                                 u16* __restrict__ sg,
                                                 u16* __restrict__ hi,
                                                 u16* __restrict__ lo) {
    const int t = threadIdx.x;
    __shared__ float sc[128], sh[128];
    if (t < 128) {
        float mean = st[t] * (1.f / 131072.f);
        float var = fmaxf(st[128 + t] * (1.f / 131072.f) - mean * mean, 0.f);
        float scale = rsqrtf(var + 1e-5f) * g[t];
        sc[t] = scale;
        sh[t] = b[t] - mean * scale;
    }
    __syncthreads();
    size_t i = ((size_t)blockIdx.x * 256 + t) * 4;
    int c0 = (int)(i & 127);
    float4v v = *(const float4v*)(src + i);
    ushort4v hv, lv, sv;
#pragma unroll
    for (int k = 0; k < 4; k++) {
        float y = fminf(fmaxf(v[k] * sc[c0 + k] + sh[c0 + k], -1.f), 1.f);
        hv[k] = f2bf(y);
        lv[k] = lo_bf(y, hv[k]);
        sv[k] = signbf(y);
    }
    *(ushort4v*)(sg + i) = sv;
    *(ushort4v*)(hi + i) = hv;
    *(ushort4v*)(lo + i) = lv;
}

// ---------------- weight prepack; BIN = standardize+sign, else hi+lo split ----------------
// Block 0 also zeroes the stats accumulator (replaces the stk memset).
template <bool BIN>
__global__ __launch_bounds__(256) void prepack_kernel(const float* __restrict__ w,
                                                      u16* __restrict__ apk,
                                                      u16* __restrict__ apkLo,
                                                      int Cin, int Cout,
                                                      float* __restrict__ stz) {
    const int t = threadIdx.x, o = blockIdx.x;
    if (o == 0) {
        stz[t] = 0.f; stz[256 + t] = 0.f; stz[512 + t] = 0.f; stz[768 + t] = 0.f;
    }
    const int E = Cin * 9;
    float m = 0.f;
    if (BIN) {
        float s = 0.f;
        for (int e = t; e < E; e += 256) s += w[o * E + e];
        __shared__ float Ls[256];
        Ls[t] = s;
        __syncthreads();
        for (int stp = 128; stp > 0; stp >>= 1) {
            if (t < stp) Ls[t] += Ls[t + stp];
            __syncthreads();
        }
        m = Ls[0] / (float)E;
    }
    const int CC = Cin >> 5, COT = Cout >> 7;
    for (int e = t; e < E; e += 256) {
        int ci = e / 9, tap = e % 9;
        float raw = w[o * E + e];
        int idx = ((tap * CC + (ci >> 5)) * COT + (o >> 7)) * 4096 + (o & 127) * 32 + (ci & 31);
        if (BIN) {
            apk[idx] = signbf(raw - m);
        } else {
            u16 hi = f2bf(raw);
            apk[idx] = hi;
            apkLo[idx] = lo_bf(raw, hi);
        }
    }
}

// ---------------- implicit-GEMM MFMA conv (8 waves / 512 threads) + fused stats ----------------
// BIN: single pass (sign weights/acts, int16 out — exact).
// real: ONE traversal, 3 MFMA terms per tap (Whi.Bhi + Whi.Blo + Wlo.Bhi),
//       out stored as bf16 hi + bf16 lo (fp32-accurate pair).
// A-fragments direct from prepacked global weights (register ping-pong).
// B-fragments: register ping-pong from double-buffered LDS. Tap t issues
// tap t+1's A+B prefetch, then sched_barrier(0), then tap t's MFMA cluster
// (setprio 1). One barrier per chunk. Epilogue: per-channel (sum,sumsq)
// shfl-reduced over l15, LDS-combined, one global atomicAdd per thread.
template <bool POOL, bool BIN>
__global__ __launch_bounds__(512, 2) void conv_mfma_kernel(
    const u16* __restrict__ act, const u16* __restrict__ actLo,
    const u16* __restrict__ apk, const u16* __restrict__ apkLo,
    u16* __restrict__ out, u16* __restrict__ outLo,
    int Cin, int Cout, int H, int W,
    float* __restrict__ st) {
    const int HW = H * W;
    const int t = threadIdx.x;
    const int wave = t >> 6, lane = t & 63;
    const int l15 = lane & 15, quad = lane >> 4;
    const int wm = wave >> 1, wn = wave & 1;   // wm 0..3 (32 co rows each)

    const int col0 = blockIdx.x * 128;
    const int cot = blockIdx.y;
    const int CC = Cin >> 5;
    const int COT = Cout >> 7;
    const bool two = (HW < 128);          // 128 cols span two images (HW==64)
    const int Wp = W + 2;
    const int nrows = two ? 2 * (H + 2) : (128 / W + 2);
    const int n0 = col0 / HW;
    const int h0 = two ? 0 : (col0 % HW) / W;

    __shared__ __align__(16) u16 BsH[2][8160];                       // dbuf [cell][40]
    __shared__ __align__(16) u16 BsL[BIN ? 1 : 2][BIN ? 16 : 8160];
    __shared__ float Sred[128], Qred[128];

    int bbase[4], gcol[4];
#pragma unroll
    for (int ni = 0; ni < 4; ni++) {
        int c = wn * 64 + ni * 16 + l15;
        int g = col0 + c;
        int n = g / HW; int hw = g % HW; int h = hw / W; int w = hw % W;
        gcol[ni] = g;
        int rb = two ? ((n - n0) * (H + 2) + h) : (h - h0);
        bbase[ni] = (rb * Wp + w) * 40 + quad * 8;
    }

    // ---- hoisted B-staging address math (cc-invariant) ----
    const int bgroups = nrows * Wp * 4;   // <= 1024 for all stages
    int svalid[2]; size_t sgoff[2]; int sloff[2];
#pragma unroll
    for (int j = 0; j < 2; j++) {
        int idx = t + j * 512;
        svalid[j] = 0; sgoff[j] = 0; sloff[j] = 0;
        if (idx < bgroups) {
            int cig = idx & 3;
            int rest = idx >> 2;
            int wp = rest % Wp;
            int srow = rest / Wp;
            int n, gh;
            if (two) { n = n0 + srow / (H + 2); gh = srow % (H + 2) - 1; }
            else     { n = n0; gh = h0 + srow - 1; }
            int gw = wp - 1;
            sloff[j] = (srow * Wp + wp) * 40 + cig * 8;
            if (gh >= 0 && gh < H && gw >= 0 && gw < W) {
                svalid[j] = 2;
                sgoff[j] = ((size_t)(n * HW + gh * W + gw)) * Cin + cig * 8;
            } else {
                svalid[j] = 1;   // in-range LDS cell, zero fill
            }
        }
    }

    float4v acc[2][4];
    const float4v zf = {0.f, 0.f, 0.f, 0.f};
#pragma unroll
    for (int mi = 0; mi < 2; mi++)
#pragma unroll
        for (int ni = 0; ni < 4; ni++) acc[mi][ni] = zf;

    const size_t tapstride = (size_t)CC * COT * 4096;
    // A-fragment offset within a tap tile: (wm*32 + l15) rows of 32 ci
    const int arow0 = wm * 1024 + l15 * 32 + quad * 8;

    short8 ahP[2][2];                     // ping-pong A-hi frags
    short8 alP[2][2];                     // ping-pong A-lo frags (real only)
    short8 ah0N[2], al0N[2];              // cross-chunk tap-0 A prefetch
    short8 bhP[2][4];                     // ping-pong B-hi frags
    short8 blP[2][4];                     // ping-pong B-lo frags (real only)
    short8 svh[2], svl[2];                // reg-staged B for next chunk
    const short8 z8 = {0, 0, 0, 0, 0, 0, 0, 0};

    // ---- prologue: stage chunk 0 into buf 0, load tap-0 A, then tap-0 B frags ----
    {
        const u16* ab0 = apk + ((size_t)cot) * 4096;
        const u16* ab0L = apkLo + ((size_t)cot) * 4096;
#pragma unroll
        for (int mi = 0; mi < 2; mi++) {
            ahP[0][mi] = *(const short8*)(ab0 + arow0 + mi * 512);
            if (!BIN) alP[0][mi] = *(const short8*)(ab0L + arow0 + mi * 512);
        }
#pragma unroll
        for (int j = 0; j < 2; j++) {
            svh[j] = z8; svl[j] = z8;
            if (svalid[j] == 2) {
                svh[j] = *(const short8*)(act + sgoff[j]);
                if (!BIN) svl[j] = *(const short8*)(actLo + sgoff[j]);
            }
        }
#pragma unroll
        for (int j = 0; j < 2; j++) {
            if (svalid[j]) {
                *(short8*)&BsH[0][sloff[j]] = svh[j];
                if (!BIN) *(short8*)&BsL[0][sloff[j]] = svl[j];
            }
        }
        if (t < 128) { Sred[t] = 0.f; Qred[t] = 0.f; }
        __syncthreads();
        // tap-0 B fragments (boff = (0*Wp+0)*40 = 0)
#pragma unroll
        for (int ni = 0; ni < 4; ni++) {
            bhP[0][ni] = *(const short8*)&BsH[0][bbase[ni]];
            if (!BIN) blP[0][ni] = *(const short8*)&BsL[0][bbase[ni]];
        }
    }

    for (int cc = 0; cc < CC; cc++) {
        const int cur = cc & 1, nx = cur ^ 1;
        const bool more = (cc + 1 < CC);
        const u16* ab = apk + ((size_t)(cc * COT + cot)) * 4096;
        const u16* abL = apkLo + ((size_t)(cc * COT + cot)) * 4096;

        // issue next chunk's B global loads + tap-0 A loads (consumed after taps)
        if (more) {
            const size_t ccb = (size_t)(cc + 1) * 32;
#pragma unroll
            for (int j = 0; j < 2; j++) {
                svh[j] = z8; svl[j] = z8;
                if (svalid[j] == 2) {
                    svh[j] = *(const short8*)(act + sgoff[j] + ccb);
                    if (!BIN) svl[j] = *(const short8*)(actLo + sgoff[j] + ccb);
                }
            }
            const u16* abN = apk + ((size_t)((cc + 1) * COT + cot)) * 4096;
            const u16* abNL = apkLo + ((size_t)((cc + 1) * COT + cot)) * 4096;
#pragma unroll
            for (int mi = 0; mi < 2; mi++) {
                ah0N[mi] = *(const short8*)(abN + arow0 + mi * 512);
                if (!BIN) al0N[mi] = *(const short8*)(abNL + arow0 + mi * 512);
            }
        }

#pragma unroll
        for (int tap = 0; tap < 9; tap++) {
            const int curp = tap & 1, nxp = curp ^ 1;
            if (tap < 8) {
                // A prefetch tap+1 (global, L1-resident)
                const u16* at = ab + (size_t)(tap + 1) * tapstride;
#pragma unroll
                for (int mi = 0; mi < 2; mi++)
                    ahP[nxp][mi] = *(const short8*)(at + arow0 + mi * 512);
                if (!BIN) {
                    const u16* atL = abL + (size_t)(tap + 1) * tapstride;
#pragma unroll
                    for (int mi = 0; mi < 2; mi++)
                        alP[nxp][mi] = *(const short8*)(atL + arow0 + mi * 512);
                }
                // B prefetch tap+1 (LDS)
                const int kh1 = (tap + 1) / 3, kw1 = (tap + 1) % 3;
                const int boff1 = (kh1 * Wp + kw1) * 40;
#pragma unroll
                for (int ni = 0; ni < 4; ni++) {
                    bhP[nxp][ni] = *(const short8*)&BsH[cur][bbase[ni] + boff1];
                    if (!BIN) blP[nxp][ni] = *(const short8*)&BsL[cur][bbase[ni] + boff1];
                }
            }
            // hard fence: prefetch issues above cannot sink below; MFMAs
            // below cannot hoist above.
            __builtin_amdgcn_sched_barrier(0);
            __builtin_amdgcn_s_setprio(1);
            if (BIN) {
#pragma unroll
                for (int mi = 0; mi < 2; mi++)
#pragma unroll
                    for (int ni = 0; ni < 4; ni++)
                        acc[mi][ni] = __builtin_amdgcn_mfma_f32_16x16x32_bf16(
                            ahP[curp][mi], bhP[curp][ni], acc[mi][ni], 0, 0, 0);
            } else {
                // three 8-MFMA sweeps: each acc has dep distance 8
#pragma unroll
                for (int mi = 0; mi < 2; mi++)
#pragma unroll
                    for (int ni = 0; ni < 4; ni++)
                        acc[mi][ni] = __builtin_amdgcn_mfma_f32_16x16x32_bf16(
                            ahP[curp][mi], bhP[curp][ni], acc[mi][ni], 0, 0, 0);
#pragma unroll
                for (int mi = 0; mi < 2; mi++)
#pragma unroll
                    for (int ni = 0; ni < 4; ni++)
                        acc[mi][ni] = __builtin_amdgcn_mfma_f32_16x16x32_bf16(
                            ahP[curp][mi], blP[curp][ni], acc[mi][ni], 0, 0, 0);
#pragma unroll
                for (int mi = 0; mi < 2; mi++)
#pragma unroll
                    for (int ni = 0; ni < 4; ni++)
                        acc[mi][ni] = __builtin_amdgcn_mfma_f32_16x16x32_bf16(
                            alP[curp][mi], bhP[curp][ni], acc[mi][ni], 0, 0, 0);
            }
            __builtin_amdgcn_s_setprio(0);
        }

        if (more) {
            // write staged B into the other buffer, then one barrier
#pragma unroll
            for (int j = 0; j < 2; j++) {
                if (svalid[j]) {
                    *(short8*)&BsH[nx][sloff[j]] = svh[j];
                    if (!BIN) *(short8*)&BsL[nx][sloff[j]] = svl[j];
                }
            }
            __syncthreads();
            // install prefetched tap-0 A and load tap-0 B frags for next chunk
#pragma unroll
            for (int mi = 0; mi < 2; mi++) {
                ahP[0][mi] = ah0N[mi];
                if (!BIN) alP[0][mi] = al0N[mi];
            }
#pragma unroll
            for (int ni = 0; ni < 4; ni++) {
                bhP[0][ni] = *(const short8*)&BsH[nx][bbase[ni]];
                if (!BIN) blP[0][ni] = *(const short8*)&BsL[nx][bbase[ni]];
            }
        }
    }

    const int cobase = cot * 128 + wm * 32 + quad * 4;
    // per-thread stats accumulators (channel = cobase + mi*16 + k, l15/ni-invariant)
    float cs[2][4] = {{0.f, 0.f, 0.f, 0.f}, {0.f, 0.f, 0.f, 0.f}};
    float cq[2][4] = {{0.f, 0.f, 0.f, 0.f}, {0.f, 0.f, 0.f, 0.f}};
    // store helper: BIN -> int16 exact; real -> bf16 hi + bf16 lo
    auto store4 = [&](size_t off, float4v v, int mi) {
#pragma unroll
        for (int k = 0; k < 4; k++) {
            cs[mi][k] += v[k];
            cq[mi][k] += v[k] * v[k];
        }
        if (BIN) {
            ushort4v r;
#pragma unroll
            for (int k = 0; k < 4; k++) r[k] = (u16)(short)(int)v[k];
            *(ushort4v*)(out + off) = r;
        } else {
            ushort4v hi, lo;
#pragma unroll
            for (int k = 0; k < 4; k++) {
                hi[k] = f2bf(v[k]);
                lo[k] = lo_bf(v[k], hi[k]);
            }
            *(ushort4v*)(out + off) = hi;
            *(ushort4v*)(outLo + off) = lo;
        }
    };

    if (!POOL) {
#pragma unroll
        for (int mi = 0; mi < 2; mi++)
#pragma unroll
            for (int ni = 0; ni < 4; ni++)
                store4((size_t)gcol[ni] * Cout + cobase + mi * 16, acc[mi][ni], mi);
    } else {
        const int pH = H >> 1, pW = W >> 1;
        if (W == 32) {
#pragma unroll
            for (int mi = 0; mi < 2; mi++)
#pragma unroll
                for (int nip = 0; nip < 2; nip++) {
                    float4v v;
#pragma unroll
                    for (int k = 0; k < 4; k++)
                        v[k] = fmaxf((float)acc[mi][nip][k], (float)acc[mi][nip + 2][k]);
#pragma unroll
                    for (int k = 0; k < 4; k++) {
                        float vv = v[k];
                        v[k] = fmaxf(vv, __shfl_xor(vv, 1, 64));
                    }
                    if ((l15 & 1) == 0) {
                        int pw = nip * 8 + (l15 >> 1);
                        int ph = (h0 >> 1) + wn;
                        int prow = (n0 * pH + ph) * pW + pw;
                        store4((size_t)prow * Cout + cobase + mi * 16, v, mi);
                    }
                }
        } else if (W == 16) {
#pragma unroll
            for (int mi = 0; mi < 2; mi++)
#pragma unroll
                for (int nip = 0; nip < 4; nip += 2) {
                    float4v v;
#pragma unroll
                    for (int k = 0; k < 4; k++)
                        v[k] = fmaxf((float)acc[mi][nip][k], (float)acc[mi][nip + 1][k]);
#pragma unroll
                    for (int k = 0; k < 4; k++) {
                        float vv = v[k];
                        v[k] = fmaxf(vv, __shfl_xor(vv, 1, 64));
                    }
                    if ((l15 & 1) == 0) {
                        int pw = l15 >> 1;
                        int ph = (h0 + wn * 4 + nip) >> 1;
                        int prow = (n0 * pH + ph) * pW + pw;
                        store4((size_t)prow * Cout + cobase + mi * 16, v, mi);
                    }
                }
        } else {  // W == 8, two-image: n = n0 + wn, h = ni*2 + (l15>>3), w = l15&7
#pragma unroll
            for (int mi = 0; mi < 2; mi++)
#pragma unroll
                for (int ni = 0; ni < 4; ni++) {
                    float4v v = acc[mi][ni];
#pragma unroll
                    for (int k = 0; k < 4; k++) {
                        float vv = v[k];
                        vv = fmaxf(vv, __shfl_xor(vv, 1, 64));
                        v[k] = fmaxf(vv, __shfl_xor(vv, 8, 64));
                    }
                    if ((l15 & 9) == 0) {
                        int pw = l15 >> 1;
                        int ph = ni;
                        int n = n0 + wn;
                        int prow = (n * pH + ph) * pW + pw;
                        store4((size_t)prow * Cout + cobase + mi * 16, v, mi);
                    }
                }
        }
    }

    // ---- fused per-channel batch stats ----
#pragma unroll
    for (int mi = 0; mi < 2; mi++)
#pragma unroll
        for (int k = 0; k < 4; k++) {
            float s = cs[mi][k], q = cq[mi][k];
            s += __shfl_xor(s, 1, 64);  q += __shfl_xor(q, 1, 64);
            s += __shfl_xor(s, 2, 64);  q += __shfl_xor(q, 2, 64);
            s += __shfl_xor(s, 4, 64);  q += __shfl_xor(q, 4, 64);
            s += __shfl_xor(s, 8, 64);  q += __shfl_xor(q, 8, 64);
            if (l15 == 0) {
                int cl = wm * 32 + mi * 16 + quad * 4 + k;
                atomicAdd(&Sred[cl], s);
                atomicAdd(&Qred[cl], q);
            }
        }
    __syncthreads();
    if (t < 128) {
        atomicAdd(&st[cot * 128 + t], Sred[t]);
        atomicAdd(&st[Cout + cot * 128 + t], Qred[t]);
    }
}

// ---------------- BN + hardtanh; acts (mode 1=real hi+lo, 2=sign) + fp32 NCHW d_out ----------------
template <bool BIN>
__global__ __launch_bounds__(256) void bn_apply_kernel(const u16* __restrict__ src,
                                                       const u16* __restrict__ srcLo,
                                                       int C, int HW,
                                                       const float* __restrict__ st, float cntinv,
                                                       const float* __restrict__ g,
                                                       const float* __restrict__ b,
                                                       float* __restrict__ dout,
                                                       float* __restrict__ dout2,
                                                       u16* __restrict__ act,
                                                       u16* __restrict__ actLo,
                                                       int act_mode) {
    const int t = threadIdx.x;
    const int cl = t & 63, rl = t >> 6;
    const int c = blockIdx.y * 64 + cl;
    const float mean = st[c] * cntinv;
    float var = st[C + c] * cntinv - mean * mean;
    var = fmaxf(var, 0.f);
    const float scale = rsqrtf(var + 1e-5f) * g[c];
    const float shift = b[c] - mean * scale;
    __shared__ float T[64][65];
#pragma unroll
    for (int i = 0; i < 16; i++) {
        int rlocal = rl + i * 4;
        int row = blockIdx.x * 64 + rlocal;
        size_t idx = (size_t)row * C + c;
        float v = BIN ? (float)(short)src[idx] : (bf2f(src[idx]) + bf2f(srcLo[idx]));
        float y = fminf(fmaxf(v * scale + shift, -1.f), 1.f);
        if (act_mode == 1) {
            u16 hi = f2bf(y);
            act[idx] = hi;
            actLo[idx] = lo_bf(y, hi);
        } else if (act_mode == 2) {
            act[idx] = signbf(y);
        }
        T[rlocal][cl] = y;
    }
    __syncthreads();
#pragma unroll
    for (int i = 0; i < 16; i++) {
        int clocal = rl + i * 4;
        int cg = blockIdx.y * 64 + clocal;
        int rglob = blockIdx.x * 64 + cl;
        int n = rglob / HW, hw = rglob % HW;
        size_t o = ((size_t)n * C + cg) * HW + hw;
        float val = T[cl][clocal];
        dout[o] = val;
        if (dout2) dout2[o] = val;
    }
}

// ---------------- FC: [128,8192] @ [10,8192]^T + b (all fp32) ----------------
__global__ __launch_bounds__(256) void fc_kernel(const float* __restrict__ penul,
                                                 const float* __restrict__ fcw,
                                                 const float* __restrict__ fcb,
                                                 float* __restrict__ out) {
    const int t = threadIdx.x, n = blockIdx.x;
    float acc[10];
#pragma unroll
    for (int j = 0; j < 10; j++) acc[j] = 0.f;
    for (int i = t; i < 8192; i += 256) {
        float p = penul[n * 8192 + i];
#pragma unroll
        for (int j = 0; j < 10; j++) acc[j] += p * fcw[j * 8192 + i];
    }
    __shared__ float L[10][256];
#pragma unroll
    for (int j = 0; j < 10; j++) L[j][t] = acc[j];
    __syncthreads();
    for (int s = 128; s > 0; s >>= 1) {
        if (t < s) {
#pragma unroll
            for (int j = 0; j < 10; j++) L[j][t] += L[j][t + s];
        }
        __syncthreads();
    }
    if (t < 10) out[n * 10 + t] = L[t][0] + fcb[t];
}

extern "C" void kernel_launch(void* const* d_in, const int* in_sizes, int n_in,
                              void* d_out, int out_size, void* d_ws, size_t ws_size,
                              hipStream_t stream) {
    (void)in_sizes; (void)n_in; (void)out_size; (void)ws_size;

    const float* X = (const float*)d_in[0];
    const float* W0 = (const float*)d_in[1];
    const float* Wl[5] = {(const float*)d_in[2], (const float*)d_in[3], (const float*)d_in[4],
                          (const float*)d_in[5], (const float*)d_in[6]};
    const float* FCW = (const float*)d_in[7];
    const float* FCB = (const float*)d_in[8];
    const float* G[6]; const float* Bb[6];
    for (int i = 0; i < 6; i++) { G[i] = (const float*)d_in[9 + 2 * i]; Bb[i] = (const float*)d_in[10 + 2 * i]; }

    float* OUT = (float*)d_out;
    char* ws = (char*)d_ws;

    // ws layout (bytes), all disjoint, total 93,329,408 (R6-proven):
    u16* apk   = (u16*)(ws);               // [0,          4,718,592)
    u16* apkLo = (u16*)(ws + 4718592);     // [4,718,592,  9,437,184)
    float* st0 = (float*)(ws + 9437184);   // [9,437,184,  9,439,232)
    float* stk = (float*)(ws + 9439232);   // [9,439,232,  9,443,328)
    u16* F     = (u16*)(ws + 9443328);     // 8,388,608 elems (hi / int16)
    u16* Flo   = (u16*)(ws + 26220544);    // 8,388,608 elems (lo, real)
    u16* AB    = (u16*)(ws + 42997760);    // 8,388,608 elems
    u16* AR    = (u16*)(ws + 59774976);    // 8,388,608 elems
    u16* ARlo  = (u16*)(ws + 76552192);    // 8,388,608 elems

    // Stage-0 arenas: C0 in ws (F..AR range, dead until stage 1); sign acts SG
    // and real hi/lo acts in dead d_out regions (R8-proven lifetimes).
    float* C0 = (float*)(ws + 9443328);
    u16* SG   = (u16*)(OUT + 26215680);
    u16* X0   = (u16*)(OUT + 9438464);
    u16* X0lo = (u16*)(OUT + 17827072);

    float* O_out = OUT;
    float* O_pen = OUT + 1280;
    float* O_L1b = OUT + 1049856;
    float* O_L1r = OUT + 5244160;
    float* O_L2b = OUT + 9438464;
    float* O_L2r = OUT + 17827072;
    float* O_L3b = OUT + 26215680;
    float* O_L3r = OUT + 28312832;
    float* O_L4b = OUT + 30409984;
    float* O_L4r = OUT + 34604288;
    float* O_L5b = OUT + 38798592;
    float* O_L5r = OUT + 39847168;

    // ---- stage 0: conv0 (fused stats) -> bn apply (sign + hi/lo)
    hipMemsetAsync(st0, 0, 2048, stream);
    conv0_main<<<4096, 256, 0, stream>>>(X, W0, C0, st0);
    bn0_apply<<<16384, 256, 0, stream>>>(C0, st0, G[0], Bb[0], SG, X0, X0lo);

    struct Stage {
        const float* w; int Cin, Cout, H, W; bool pool;
        dim3 cgrid; dim3 bgrid; int bHW; float cntinv;
        float* db; float* dr;
    };
    const Stage S[5] = {
        {Wl[0], 128, 128, 32, 32, true,  dim3(1024, 1), dim3(512, 2), 256, 1.f / 32768.f, O_L1b, O_L1r},
        {Wl[1], 128, 256, 16, 16, false, dim3(256, 2),  dim3(512, 4), 256, 1.f / 32768.f, O_L2b, O_L2r},
        {Wl[2], 256, 256, 16, 16, true,  dim3(256, 2),  dim3(128, 4), 64,  1.f / 8192.f,  O_L3b, O_L3r},
        {Wl[3], 256, 512, 8, 8,   false, dim3(64, 4),   dim3(128, 8), 64,  1.f / 8192.f,  O_L4b, O_L4r},
        {Wl[4], 512, 512, 8, 8,   true,  dim3(64, 4),   dim3(32, 8),  16,  1.f / 2048.f,  O_L5b, O_L5r},
    };

    for (int k = 0; k < 5; k++) {
        const Stage& s = S[k];
        const u16* inB = (k == 0) ? SG : AB;
        const u16* inR = (k == 0) ? X0 : AR;
        const u16* inRlo = (k == 0) ? X0lo : ARlo;

        // ---- binary branch (exact: sign weights/acts, int16 conv-out)
        prepack_kernel<true><<<s.Cout, 256, 0, stream>>>(s.w, apk, nullptr, s.Cin, s.Cout, stk);
        if (s.pool) conv_mfma_kernel<true, true><<<s.cgrid, 512, 0, stream>>>(inB, nullptr, apk, apk, F, nullptr, s.Cin, s.Cout, s.H, s.W, stk);
        else        conv_mfma_kernel<false, true><<<s.cgrid, 512, 0, stream>>>(inB, nullptr, apk, apk, F, nullptr, s.Cin, s.Cout, s.H, s.W, stk);
        bn_apply_kernel<true><<<s.bgrid, 256, 0, stream>>>(F, nullptr, s.Cout, s.bHW, stk, s.cntinv,
                                                           G[k + 1], Bb[k + 1], s.db,
                                                           (k == 4) ? O_pen : nullptr,
                                                           AB, nullptr, (k == 4) ? 0 : 2);

        // ---- real branch (single traversal, 3-term split-bf16; out hi+lo)
        prepack_kernel<false><<<s.Cout, 256, 0, stream>>>(s.w, apk, apkLo, s.Cin, s.Cout, stk);
        if (s.pool) conv_mfma_kernel<true, false><<<s.cgrid, 512, 0, stream>>>(inR, inRlo, apk, apkLo, F, Flo, s.Cin, s.Cout, s.H, s.W, stk);
        else        conv_mfma_kernel<false, false><<<s.cgrid, 512, 0, stream>>>(inR, inRlo, apk, apkLo, F, Flo, s.Cin, s.Cout, s.H, s.W, stk);
        bn_apply_kernel<false><<<s.bgrid, 256, 0, stream>>>(F, Flo, s.Cout, s.bHW, stk, s.cntinv,
                                                            G[k + 1], Bb[k + 1], s.dr, nullptr,
                                                            AR, ARlo, (k == 4) ? 0 : 1);
    }

    // ---- fc
    fc_kernel<<<128, 256, 0, stream>>>(O_pen, FCW, FCB, O_out);
}